// Round 1
// baseline (216.062 us; speedup 1.0000x reference)
//
#include <hip/hip_runtime.h>
#include <hip/hip_bf16.h>
#include <math.h>

#define N_NODES 16384
#define B_MOL   1024
#define K_CONF  16
#define C_DIM   128
#define HID_DIM 256

// ---------------------------------------------------------------------------
// GEMM: Y[r,m] = act( sum_k X[r,k]*W[k,m] + bias[m] ), rows = grid.x*128,
// cols = grid.y*128. BM=BN=128, BK=32, 256 threads, 8x8 accum per thread.
// ---------------------------------------------------------------------------
__global__ __launch_bounds__(256)
void gemm128(const float* __restrict__ X, const float* __restrict__ W,
             const float* __restrict__ bias, float* __restrict__ Y,
             int K, int M, int act, float slope) {
    __shared__ float As[32][132];   // k-major: As[k][row]
    __shared__ float Bs[32][132];   // k-major: Bs[k][col]
    int tid = threadIdx.x;
    int tx = tid & 15, ty = tid >> 4;
    int rowBase = blockIdx.x * 128;
    int colBase = blockIdx.y * 128;

    float acc[8][8];
    #pragma unroll
    for (int i = 0; i < 8; ++i)
        #pragma unroll
        for (int j = 0; j < 8; ++j) acc[i][j] = 0.0f;

    for (int k0 = 0; k0 < K; k0 += 32) {
        #pragma unroll
        for (int it = 0; it < 4; ++it) {
            int idx = tid + it * 256;
            // A tile: 128 rows x 32 k  (transpose into k-major LDS)
            int r  = idx >> 3;
            int kq = idx & 7;
            float4 va = *(const float4*)&X[(size_t)(rowBase + r) * K + k0 + kq * 4];
            As[kq * 4 + 0][r] = va.x;
            As[kq * 4 + 1][r] = va.y;
            As[kq * 4 + 2][r] = va.z;
            As[kq * 4 + 3][r] = va.w;
            // B tile: 32 k x 128 cols (already k-major)
            int kr = idx >> 5;
            int cq = idx & 31;
            *(float4*)&Bs[kr][cq * 4] =
                *(const float4*)&W[(size_t)(k0 + kr) * M + colBase + cq * 4];
        }
        __syncthreads();

        #pragma unroll
        for (int k = 0; k < 32; ++k) {
            float4 a0 = *(float4*)&As[k][ty * 4];
            float4 a1 = *(float4*)&As[k][ty * 4 + 64];
            float4 b0 = *(float4*)&Bs[k][tx * 4];
            float4 b1 = *(float4*)&Bs[k][tx * 4 + 64];
            float av[8] = {a0.x, a0.y, a0.z, a0.w, a1.x, a1.y, a1.z, a1.w};
            float bv[8] = {b0.x, b0.y, b0.z, b0.w, b1.x, b1.y, b1.z, b1.w};
            #pragma unroll
            for (int i = 0; i < 8; ++i)
                #pragma unroll
                for (int j = 0; j < 8; ++j)
                    acc[i][j] += av[i] * bv[j];
        }
        __syncthreads();
    }

    #pragma unroll
    for (int i = 0; i < 8; ++i) {
        int rr = rowBase + ty * 4 + (i & 3) + ((i >> 2) << 6);
        #pragma unroll
        for (int jj = 0; jj < 2; ++jj) {
            int cc = colBase + tx * 4 + (jj << 6);
            float4 bv = *(const float4*)&bias[cc];
            float4 o;
            o.x = acc[i][jj * 4 + 0] + bv.x;
            o.y = acc[i][jj * 4 + 1] + bv.y;
            o.z = acc[i][jj * 4 + 2] + bv.z;
            o.w = acc[i][jj * 4 + 3] + bv.w;
            if (act) {
                o.x = o.x >= 0.f ? o.x : slope * o.x;
                o.y = o.y >= 0.f ? o.y : slope * o.y;
                o.z = o.z >= 0.f ? o.z : slope * o.z;
                o.w = o.w >= 0.f ? o.w : slope * o.w;
            }
            *(float4*)&Y[(size_t)rr * M + cc] = o;
        }
    }
}

// ---------------------------------------------------------------------------
// GATv2 attention within each 16-node molecule (dense, incl. self-loops).
// XL/XR: [N, 2*128] (head-major). att: [2][128]. Writes Xout: [N,128].
// ---------------------------------------------------------------------------
__global__ __launch_bounds__(256)
void gat_attn(const float* __restrict__ XL, const float* __restrict__ XR,
              const float* __restrict__ att, const float* __restrict__ gbias,
              float* __restrict__ Xout) {
    int mol = blockIdx.x;
    int tid = threadIdx.x;
    __shared__ float sXL[16][260];   // pad 260: breaks same-bank stride-128 reads
    __shared__ float sXR[16][260];
    __shared__ float sAtt[256];
    __shared__ float sBias[128];
    __shared__ float sLog[32][18];   // [d*2+h][s]

    int base = mol * 16;
    for (int i = tid; i < 1024; i += 256) {
        int node = i >> 6;
        int c4   = i & 63;
        *(float4*)&sXL[node][c4 * 4] =
            *(const float4*)&XL[(size_t)(base + node) * 256 + c4 * 4];
        *(float4*)&sXR[node][c4 * 4] =
            *(const float4*)&XR[(size_t)(base + node) * 256 + c4 * 4];
    }
    sAtt[tid] = att[tid];
    if (tid < 128) sBias[tid] = gbias[tid];
    __syncthreads();

    // logits[d][h][s] = sum_c att[h][c] * leaky(xl[s][h][c] + xr[d][h][c], 0.2)
    for (int p = tid; p < 512; p += 256) {
        int d = p >> 5, h = (p >> 4) & 1, s = p & 15;
        const float* xl = &sXL[s][h * 128];
        const float* xr = &sXR[d][h * 128];
        const float* at = &sAtt[h * 128];
        float accv = 0.f;
        #pragma unroll 8
        for (int c = 0; c < 128; ++c) {
            float e = xl[c] + xr[c];
            e = e >= 0.f ? e : 0.2f * e;
            accv += at[c] * e;
        }
        sLog[d * 2 + h][s] = accv;
    }
    __syncthreads();

    // softmax over s for each (d,h)
    if (tid < 32) {
        float m = -1e30f;
        #pragma unroll
        for (int s = 0; s < 16; ++s) m = fmaxf(m, sLog[tid][s]);
        float den = 0.f;
        #pragma unroll
        for (int s = 0; s < 16; ++s) {
            float e = expf(sLog[tid][s] - m);
            sLog[tid][s] = e;
            den += e;
        }
        float inv = 1.0f / den;
        #pragma unroll
        for (int s = 0; s < 16; ++s) sLog[tid][s] *= inv;
    }
    __syncthreads();

    // out[d][c] = 0.5 * sum_h sum_s alpha[d][h][s]*xl[s][h][c] + bias[c]
    int c = tid & 127;
    int db = tid >> 7;           // 0 or 1
    #pragma unroll
    for (int i = 0; i < 8; ++i) {
        int d = db + 2 * i;
        float accv = 0.f;
        #pragma unroll
        for (int h = 0; h < 2; ++h) {
            const float* al = sLog[d * 2 + h];
            #pragma unroll
            for (int s = 0; s < 16; ++s)
                accv += al[s] * sXL[s][h * 128 + c];
        }
        Xout[(size_t)(base + d) * 128 + c] = 0.5f * accv + sBias[c];
    }
}

// ---------------------------------------------------------------------------
// Gate dot + segment softmax + pooling. X2: [N,128], H2: [N,256].
// out[0:131072] = h_pool, out[131072:147456] = scores.
// ---------------------------------------------------------------------------
__global__ __launch_bounds__(256)
void gate_pool(const float* __restrict__ X2, const float* __restrict__ H2,
               const float* __restrict__ gW3, const float* __restrict__ gb3,
               float* __restrict__ out) {
    int mol = blockIdx.x;
    int tid = threadIdx.x;
    __shared__ float sW3[256];
    __shared__ float sg[16];
    __shared__ float ssc[16];

    sW3[tid] = gW3[tid];
    __syncthreads();

    int j = tid >> 4;        // node within molecule
    int lane = tid & 15;
    const float* h2 = H2 + (size_t)(mol * 16 + j) * 256;
    float p = 0.f;
    #pragma unroll
    for (int c = lane; c < 256; c += 16) p += h2[c] * sW3[c];
    #pragma unroll
    for (int off = 8; off; off >>= 1) p += __shfl_down(p, off, 16);
    if (lane == 0) sg[j] = p + gb3[0];
    __syncthreads();

    if (tid < 16) {
        float m = -1e30f;
        #pragma unroll
        for (int s = 0; s < 16; ++s) m = fmaxf(m, sg[s]);
        float e = expf(sg[tid] - m);
        float den = e;
        #pragma unroll
        for (int off = 8; off; off >>= 1) den += __shfl_xor(den, off, 16);
        float sc = e / den;
        ssc[tid] = sc;
        out[131072 + mol * 16 + tid] = sc;
    }
    __syncthreads();

    if (tid < 128) {
        const float* xb = X2 + (size_t)(mol * 16) * 128;
        float accv = 0.f;
        #pragma unroll
        for (int s = 0; s < 16; ++s) accv += ssc[s] * xb[s * 128 + tid];
        out[mol * 128 + tid] = accv;
    }
}

// ---------------------------------------------------------------------------
extern "C" void kernel_launch(void* const* d_in, const int* in_sizes, int n_in,
                              void* d_out, int out_size, void* d_ws, size_t ws_size,
                              hipStream_t stream) {
    (void)in_sizes; (void)n_in; (void)out_size; (void)ws_size;
    const float* H        = (const float*)d_in[0];
    const float* Wl       = (const float*)d_in[4];
    const float* bl       = (const float*)d_in[5];
    const float* Wr       = (const float*)d_in[6];
    const float* br       = (const float*)d_in[7];
    const float* att      = (const float*)d_in[8];
    const float* gat_bias = (const float*)d_in[9];
    const float* gW1      = (const float*)d_in[10];
    const float* gb1      = (const float*)d_in[11];
    const float* gW2      = (const float*)d_in[12];
    const float* gb2      = (const float*)d_in[13];
    const float* gW3      = (const float*)d_in[14];
    const float* gb3      = (const float*)d_in[15];
    float* out = (float*)d_out;

    float* A  = (float*)d_ws;                       // [N, 256]
    float* Bb = A + (size_t)N_NODES * 256;          // [N, 256]
    float* X  = Bb + (size_t)N_NODES * 256;         // [N, 128]

    dim3 gemmGrid(N_NODES / 128, 2);                // M=256 -> 2 col tiles

    // ---- layer 0 ----
    gemm128<<<gemmGrid, 256, 0, stream>>>(H, Wl, bl, A, 128, 256, 0, 0.f);
    gemm128<<<gemmGrid, 256, 0, stream>>>(H, Wr, br, Bb, 128, 256, 0, 0.f);
    gat_attn<<<B_MOL, 256, 0, stream>>>(A, Bb, att, gat_bias, X);

    // ---- layer 1 ----
    gemm128<<<gemmGrid, 256, 0, stream>>>(X, Wl + 32768, bl + 256, A, 128, 256, 0, 0.f);
    gemm128<<<gemmGrid, 256, 0, stream>>>(X, Wr + 32768, br + 256, Bb, 128, 256, 0, 0.f);
    gat_attn<<<B_MOL, 256, 0, stream>>>(A, Bb, att + 256, gat_bias + 128, X);

    // ---- gate MLP ----
    gemm128<<<gemmGrid, 256, 0, stream>>>(X, gW1, gb1, A, 128, 256, 1, 0.01f);
    gemm128<<<gemmGrid, 256, 0, stream>>>(A, gW2, gb2, Bb, 256, 256, 1, 0.01f);

    // ---- gate + softmax + pool ----
    gate_pool<<<B_MOL, 256, 0, stream>>>(X, Bb, gW3, gb3, out);
}

// Round 2
// 183.469 us; speedup vs baseline: 1.1776x; 1.1776x over previous
//
#include <hip/hip_runtime.h>
#include <hip/hip_bf16.h>
#include <math.h>

#define N_NODES 16384
#define B_MOL   1024
#define K_CONF  16
#define C_DIM   128
#define HID_DIM 256

// ---------------------------------------------------------------------------
// GEMM, 64x64 tile, BK=32, 256 threads, 4x4 accum/thread.
// Dual-output ("fused") form: blockIdx.y < halfTiles -> (WA,bA,YA),
// else -> (WB,bB,YB). M = columns of each output (stride). For a single
// GEMM pass WB=WA etc. and grid.y = halfTiles.
// ---------------------------------------------------------------------------
__global__ __launch_bounds__(256)
void gemm64(const float* __restrict__ X,
            const float* __restrict__ WA, const float* __restrict__ bA, float* __restrict__ YA,
            const float* __restrict__ WB, const float* __restrict__ bB, float* __restrict__ YB,
            int K, int M, int halfTiles, int act, float slope) {
    __shared__ float As[32][68];   // k-major: As[k][row]
    __shared__ float Bs[32][68];   // k-major: Bs[k][col]
    int tid = threadIdx.x;
    int tx = tid & 15, ty = tid >> 4;
    int rowBase = blockIdx.x * 64;

    const float* W; const float* bias; float* Y; int colBase;
    if ((int)blockIdx.y < halfTiles) {
        W = WA; bias = bA; Y = YA; colBase = blockIdx.y * 64;
    } else {
        W = WB; bias = bB; Y = YB; colBase = (blockIdx.y - halfTiles) * 64;
    }

    float acc[4][4];
    #pragma unroll
    for (int i = 0; i < 4; ++i)
        #pragma unroll
        for (int j = 0; j < 4; ++j) acc[i][j] = 0.0f;

    for (int k0 = 0; k0 < K; k0 += 32) {
        #pragma unroll
        for (int it = 0; it < 2; ++it) {
            int idx = tid + it * 256;
            // A tile: 64 rows x 32 k -> transpose to k-major
            int r  = idx >> 3;
            int kq = idx & 7;
            float4 va = *(const float4*)&X[(size_t)(rowBase + r) * K + k0 + kq * 4];
            As[kq * 4 + 0][r] = va.x;
            As[kq * 4 + 1][r] = va.y;
            As[kq * 4 + 2][r] = va.z;
            As[kq * 4 + 3][r] = va.w;
            // B tile: 32 k x 64 cols (k-major already)
            int kr = idx >> 4;
            int cq = idx & 15;
            *(float4*)&Bs[kr][cq * 4] =
                *(const float4*)&W[(size_t)(k0 + kr) * M + colBase + cq * 4];
        }
        __syncthreads();

        #pragma unroll
        for (int k = 0; k < 32; ++k) {
            float4 a = *(float4*)&As[k][ty * 4];
            float4 b = *(float4*)&Bs[k][tx * 4];
            float av[4] = {a.x, a.y, a.z, a.w};
            float bv[4] = {b.x, b.y, b.z, b.w};
            #pragma unroll
            for (int i = 0; i < 4; ++i)
                #pragma unroll
                for (int j = 0; j < 4; ++j)
                    acc[i][j] += av[i] * bv[j];
        }
        __syncthreads();
    }

    int cc = colBase + tx * 4;
    float4 bv = *(const float4*)&bias[cc];
    #pragma unroll
    for (int i = 0; i < 4; ++i) {
        int rr = rowBase + ty * 4 + i;
        float4 o;
        o.x = acc[i][0] + bv.x;
        o.y = acc[i][1] + bv.y;
        o.z = acc[i][2] + bv.z;
        o.w = acc[i][3] + bv.w;
        if (act) {
            o.x = o.x >= 0.f ? o.x : slope * o.x;
            o.y = o.y >= 0.f ? o.y : slope * o.y;
            o.z = o.z >= 0.f ? o.z : slope * o.z;
            o.w = o.w >= 0.f ? o.w : slope * o.w;
        }
        *(float4*)&Y[(size_t)rr * M + cc] = o;
    }
}

// ---------------------------------------------------------------------------
// GATv2 attention within each 16-node molecule (dense, incl. self-loops).
// XL/XR: [N, 2*128] (head-major). att: [2][128]. Writes Xout: [N,128].
// ---------------------------------------------------------------------------
__global__ __launch_bounds__(256)
void gat_attn(const float* __restrict__ XL, const float* __restrict__ XR,
              const float* __restrict__ att, const float* __restrict__ gbias,
              float* __restrict__ Xout) {
    int mol = blockIdx.x;
    int tid = threadIdx.x;
    __shared__ float sXL[16][260];   // pad 260: breaks same-bank stride-128 reads
    __shared__ float sXR[16][260];
    __shared__ float sAtt[256];
    __shared__ float sBias[128];
    __shared__ float sLog[32][18];   // [d*2+h][s]

    int base = mol * 16;
    for (int i = tid; i < 1024; i += 256) {
        int node = i >> 6;
        int c4   = i & 63;
        *(float4*)&sXL[node][c4 * 4] =
            *(const float4*)&XL[(size_t)(base + node) * 256 + c4 * 4];
        *(float4*)&sXR[node][c4 * 4] =
            *(const float4*)&XR[(size_t)(base + node) * 256 + c4 * 4];
    }
    sAtt[tid] = att[tid];
    if (tid < 128) sBias[tid] = gbias[tid];
    __syncthreads();

    // logits[d][h][s] = sum_c att[h][c] * leaky(xl[s][h][c] + xr[d][h][c], 0.2)
    for (int p = tid; p < 512; p += 256) {
        int d = p >> 5, h = (p >> 4) & 1, s = p & 15;
        const float* xl = &sXL[s][h * 128];
        const float* xr = &sXR[d][h * 128];
        const float* at = &sAtt[h * 128];
        float accv = 0.f;
        #pragma unroll 8
        for (int c = 0; c < 128; ++c) {
            float e = xl[c] + xr[c];
            e = e >= 0.f ? e : 0.2f * e;
            accv += at[c] * e;
        }
        sLog[d * 2 + h][s] = accv;
    }
    __syncthreads();

    // softmax over s for each (d,h)
    if (tid < 32) {
        float m = -1e30f;
        #pragma unroll
        for (int s = 0; s < 16; ++s) m = fmaxf(m, sLog[tid][s]);
        float den = 0.f;
        #pragma unroll
        for (int s = 0; s < 16; ++s) {
            float e = expf(sLog[tid][s] - m);
            sLog[tid][s] = e;
            den += e;
        }
        float inv = 1.0f / den;
        #pragma unroll
        for (int s = 0; s < 16; ++s) sLog[tid][s] *= inv;
    }
    __syncthreads();

    // out[d][c] = 0.5 * sum_h sum_s alpha[d][h][s]*xl[s][h][c] + bias[c]
    int c = tid & 127;
    int db = tid >> 7;           // 0 or 1
    #pragma unroll
    for (int i = 0; i < 8; ++i) {
        int d = db + 2 * i;
        float accv = 0.f;
        #pragma unroll
        for (int h = 0; h < 2; ++h) {
            const float* al = sLog[d * 2 + h];
            #pragma unroll
            for (int s = 0; s < 16; ++s)
                accv += al[s] * sXL[s][h * 128 + c];
        }
        Xout[(size_t)(base + d) * 128 + c] = 0.5f * accv + sBias[c];
    }
}

// ---------------------------------------------------------------------------
// Gate dot + segment softmax + pooling. X2: [N,128], H2: [N,256].
// out[0:131072] = h_pool, out[131072:147456] = scores.
// ---------------------------------------------------------------------------
__global__ __launch_bounds__(256)
void gate_pool(const float* __restrict__ X2, const float* __restrict__ H2,
               const float* __restrict__ gW3, const float* __restrict__ gb3,
               float* __restrict__ out) {
    int mol = blockIdx.x;
    int tid = threadIdx.x;
    __shared__ float sW3[256];
    __shared__ float sg[16];
    __shared__ float ssc[16];

    sW3[tid] = gW3[tid];
    __syncthreads();

    int j = tid >> 4;        // node within molecule
    int lane = tid & 15;
    const float* h2 = H2 + (size_t)(mol * 16 + j) * 256;
    float p = 0.f;
    #pragma unroll
    for (int c = lane; c < 256; c += 16) p += h2[c] * sW3[c];
    #pragma unroll
    for (int off = 8; off; off >>= 1) p += __shfl_down(p, off, 16);
    if (lane == 0) sg[j] = p + gb3[0];
    __syncthreads();

    if (tid < 16) {
        float m = -1e30f;
        #pragma unroll
        for (int s = 0; s < 16; ++s) m = fmaxf(m, sg[s]);
        float e = expf(sg[tid] - m);
        float den = e;
        #pragma unroll
        for (int off = 8; off; off >>= 1) den += __shfl_xor(den, off, 16);
        float sc = e / den;
        ssc[tid] = sc;
        out[131072 + mol * 16 + tid] = sc;
    }
    __syncthreads();

    if (tid < 128) {
        const float* xb = X2 + (size_t)(mol * 16) * 128;
        float accv = 0.f;
        #pragma unroll
        for (int s = 0; s < 16; ++s) accv += ssc[s] * xb[s * 128 + tid];
        out[mol * 128 + tid] = accv;
    }
}

// ---------------------------------------------------------------------------
extern "C" void kernel_launch(void* const* d_in, const int* in_sizes, int n_in,
                              void* d_out, int out_size, void* d_ws, size_t ws_size,
                              hipStream_t stream) {
    (void)in_sizes; (void)n_in; (void)out_size; (void)ws_size;
    const float* H        = (const float*)d_in[0];
    const float* Wl       = (const float*)d_in[4];
    const float* bl       = (const float*)d_in[5];
    const float* Wr       = (const float*)d_in[6];
    const float* br       = (const float*)d_in[7];
    const float* att      = (const float*)d_in[8];
    const float* gat_bias = (const float*)d_in[9];
    const float* gW1      = (const float*)d_in[10];
    const float* gb1      = (const float*)d_in[11];
    const float* gW2      = (const float*)d_in[12];
    const float* gb2      = (const float*)d_in[13];
    const float* gW3      = (const float*)d_in[14];
    const float* gb3      = (const float*)d_in[15];
    float* out = (float*)d_out;

    float* A  = (float*)d_ws;                       // [N, 256] xl / mlp h1
    float* Bb = A + (size_t)N_NODES * 256;          // [N, 256] xr / mlp h2
    float* X  = Bb + (size_t)N_NODES * 256;         // [N, 128] layer output

    dim3 fusedGrid(N_NODES / 64, 8);                // 2048 blocks: xl + xr
    dim3 mlpGrid(N_NODES / 64, 4);                  // 1024 blocks

    // ---- layer 0: xl = H@Wl+bl -> A ; xr = H@Wr+br -> Bb ----
    gemm64<<<fusedGrid, 256, 0, stream>>>(H, Wl, bl, A, Wr, br, Bb,
                                          128, 256, 4, 0, 0.f);
    gat_attn<<<B_MOL, 256, 0, stream>>>(A, Bb, att, gat_bias, X);

    // ---- layer 1 ----
    gemm64<<<fusedGrid, 256, 0, stream>>>(X, Wl + 32768, bl + 256, A,
                                          Wr + 32768, br + 256, Bb,
                                          128, 256, 4, 0, 0.f);
    gat_attn<<<B_MOL, 256, 0, stream>>>(A, Bb, att + 256, gat_bias + 128, X);

    // ---- gate MLP ----
    gemm64<<<mlpGrid, 256, 0, stream>>>(X, gW1, gb1, A, gW1, gb1, A,
                                        128, 256, 4, 1, 0.01f);
    gemm64<<<mlpGrid, 256, 0, stream>>>(A, gW2, gb2, Bb, gW2, gb2, Bb,
                                        256, 256, 4, 1, 0.01f);

    // ---- gate + softmax + pool ----
    gate_pool<<<B_MOL, 256, 0, stream>>>(X, Bb, gW3, gb3, out);
}

// Round 3
// 153.900 us; speedup vs baseline: 1.4039x; 1.1921x over previous
//
#include <hip/hip_runtime.h>
#include <hip/hip_bf16.h>
#include <math.h>

#define N_NODES 16384
#define B_MOL   1024
#define K_CONF  16
#define C_DIM   128
#define HID_DIM 256

typedef __attribute__((ext_vector_type(8))) short short8v;
typedef __attribute__((ext_vector_type(4))) float f32x4;

static __device__ __forceinline__ unsigned short f2bf(float f) {
    unsigned int u = __float_as_uint(f);
    unsigned int r = (u + 0x7FFFu + ((u >> 16) & 1u)) >> 16;   // RNE
    return (unsigned short)r;
}
static __device__ __forceinline__ float bf2f(unsigned short h) {
    return __uint_as_float(((unsigned int)h) << 16);
}

// ---------------------------------------------------------------------------
// Weight convert: W[k][m] fp32 -> Wt[m][k] bf16 hi (at dst) + lo (at dst+256*K).
// Segments: Wl0, Wr0, Wl1, Wr1, gW1 (K=128, 32768 each), gW2 (K=256, 65536).
// ---------------------------------------------------------------------------
__global__ __launch_bounds__(256)
void conv_wt(const float* __restrict__ Wl, const float* __restrict__ Wr,
             const float* __restrict__ g1, const float* __restrict__ g2,
             unsigned short* __restrict__ wt) {
    int idx = blockIdx.x * 256 + threadIdx.x;
    const float* src; int K; size_t dst; int e;
    if      (idx <  32768) { src = Wl;         K = 128; dst = 0;      e = idx;          }
    else if (idx <  65536) { src = Wr;         K = 128; dst = 65536;  e = idx - 32768;  }
    else if (idx <  98304) { src = Wl + 32768; K = 128; dst = 131072; e = idx - 65536;  }
    else if (idx < 131072) { src = Wr + 32768; K = 128; dst = 196608; e = idx - 98304;  }
    else if (idx < 163840) { src = g1;         K = 128; dst = 262144; e = idx - 131072; }
    else if (idx < 229376) { src = g2;         K = 256; dst = 327680; e = idx - 163840; }
    else return;
    int k = e >> 8, m = e & 255;                   // M == 256 for all segments
    float v = src[e];
    unsigned short h = f2bf(v);
    unsigned short l = f2bf(v - bf2f(h));
    wt[dst + (size_t)m * K + k] = h;
    wt[dst + ((size_t)K << 8) + (size_t)m * K + k] = l;
}

// ---------------------------------------------------------------------------
// Split-bf16 MFMA GEMM: Y = act(X @ W + b). BM=64, BN=128, BK=32, 4 waves
// (2x2), wave tile 32x64 (2x4 frags of 16x16x32). W pre-transposed bf16
// hi/lo [m][k]. Dual-output: blockIdx.y < halfTiles -> set A else set B.
// ---------------------------------------------------------------------------
__global__ __launch_bounds__(256)
void gemm_mfma(const float* __restrict__ X,
               const unsigned short* __restrict__ WAh, const unsigned short* __restrict__ WAl,
               const float* __restrict__ bA, float* __restrict__ YA,
               const unsigned short* __restrict__ WBh, const unsigned short* __restrict__ WBl,
               const float* __restrict__ bB, float* __restrict__ YB,
               int K, int M, int halfTiles, int act, float slope) {
    __shared__ short Ah[64][40], Al[64][40];     // [row][k], pad 40 (80B = 20 banks)
    __shared__ short Bh[128][40], Bl[128][40];   // [col][k]

    int tid = threadIdx.x;
    int rowBase = blockIdx.x * 64;

    const unsigned short *Wh, *Wlo; const float* bias; float* Y; int colBase;
    if ((int)blockIdx.y < halfTiles) {
        Wh = WAh; Wlo = WAl; bias = bA; Y = YA; colBase = blockIdx.y * 128;
    } else {
        Wh = WBh; Wlo = WBl; bias = bB; Y = YB; colBase = (blockIdx.y - halfTiles) * 128;
    }

    int lane = tid & 63;
    int wid  = tid >> 6;
    int wy = wid & 1, wx = wid >> 1;   // 2x2 waves
    int lr = lane & 15;                // row (A) / col (B) within frag
    int kb = (lane >> 4) * 8;          // k-offset within frag

    f32x4 acc[2][4];
    #pragma unroll
    for (int i = 0; i < 2; ++i)
        #pragma unroll
        for (int j = 0; j < 4; ++j)
            acc[i][j] = (f32x4){0.f, 0.f, 0.f, 0.f};

    for (int kt = 0; kt < K; kt += 32) {
        // ---- stage A: X tile 64x32 fp32 -> hi/lo bf16 ----
        #pragma unroll
        for (int it = 0; it < 2; ++it) {
            int idx = tid + it * 256;
            int r = idx >> 3, q = idx & 7;
            float4 v = *(const float4*)&X[(size_t)(rowBase + r) * K + kt + q * 4];
            unsigned short h0 = f2bf(v.x), h1 = f2bf(v.y), h2 = f2bf(v.z), h3 = f2bf(v.w);
            *(short4*)&Ah[r][q * 4] = make_short4((short)h0, (short)h1, (short)h2, (short)h3);
            unsigned short l0 = f2bf(v.x - bf2f(h0)), l1 = f2bf(v.y - bf2f(h1));
            unsigned short l2 = f2bf(v.z - bf2f(h2)), l3 = f2bf(v.w - bf2f(h3));
            *(short4*)&Al[r][q * 4] = make_short4((short)l0, (short)l1, (short)l2, (short)l3);
        }
        // ---- stage B: Wt tile 128 cols x 32 k, already bf16 hi/lo ----
        #pragma unroll
        for (int it = 0; it < 2; ++it) {
            int idx = tid + it * 256;
            int c = idx >> 2, q = idx & 3;
            size_t off = (size_t)(colBase + c) * K + kt + q * 8;
            *(short8v*)&Bh[c][q * 8] = *(const short8v*)&Wh[off];
            *(short8v*)&Bl[c][q * 8] = *(const short8v*)&Wlo[off];
        }
        __syncthreads();

        short8v a_h[2], a_l[2], b_h[4], b_l[4];
        #pragma unroll
        for (int i = 0; i < 2; ++i) {
            a_h[i] = *(const short8v*)&Ah[wy * 32 + i * 16 + lr][kb];
            a_l[i] = *(const short8v*)&Al[wy * 32 + i * 16 + lr][kb];
        }
        #pragma unroll
        for (int j = 0; j < 4; ++j) {
            b_h[j] = *(const short8v*)&Bh[wx * 64 + j * 16 + lr][kb];
            b_l[j] = *(const short8v*)&Bl[wx * 64 + j * 16 + lr][kb];
        }
        #pragma unroll
        for (int i = 0; i < 2; ++i)
            #pragma unroll
            for (int j = 0; j < 4; ++j) {
                acc[i][j] = __builtin_amdgcn_mfma_f32_16x16x32_bf16(a_h[i], b_h[j], acc[i][j], 0, 0, 0);
                acc[i][j] = __builtin_amdgcn_mfma_f32_16x16x32_bf16(a_h[i], b_l[j], acc[i][j], 0, 0, 0);
                acc[i][j] = __builtin_amdgcn_mfma_f32_16x16x32_bf16(a_l[i], b_h[j], acc[i][j], 0, 0, 0);
            }
        __syncthreads();
    }

    // ---- epilogue: C/D layout col=lane&15, row=(lane>>4)*4+reg ----
    #pragma unroll
    for (int i = 0; i < 2; ++i) {
        int row0 = rowBase + wy * 32 + i * 16 + (lane >> 4) * 4;
        #pragma unroll
        for (int j = 0; j < 4; ++j) {
            int colL = colBase + wx * 64 + j * 16 + lr;
            float bv = bias[colL];
            #pragma unroll
            for (int rr = 0; rr < 4; ++rr) {
                float v = acc[i][j][rr] + bv;
                if (act) v = v >= 0.f ? v : slope * v;
                Y[(size_t)(row0 + rr) * M + colL] = v;
            }
        }
    }
}

// ---------------------------------------------------------------------------
// GATv2 attention within each 16-node molecule (dense, incl. self-loops).
// ---------------------------------------------------------------------------
__global__ __launch_bounds__(256)
void gat_attn(const float* __restrict__ XL, const float* __restrict__ XR,
              const float* __restrict__ att, const float* __restrict__ gbias,
              float* __restrict__ Xout) {
    int mol = blockIdx.x;
    int tid = threadIdx.x;
    __shared__ float sXL[16][260];
    __shared__ float sXR[16][260];
    __shared__ float sAtt[256];
    __shared__ float sBias[128];
    __shared__ float sLog[32][18];

    int base = mol * 16;
    for (int i = tid; i < 1024; i += 256) {
        int node = i >> 6;
        int c4   = i & 63;
        *(float4*)&sXL[node][c4 * 4] =
            *(const float4*)&XL[(size_t)(base + node) * 256 + c4 * 4];
        *(float4*)&sXR[node][c4 * 4] =
            *(const float4*)&XR[(size_t)(base + node) * 256 + c4 * 4];
    }
    sAtt[tid] = att[tid];
    if (tid < 128) sBias[tid] = gbias[tid];
    __syncthreads();

    for (int p = tid; p < 512; p += 256) {
        int d = p >> 5, h = (p >> 4) & 1, s = p & 15;
        const float4* xl = (const float4*)&sXL[s][h * 128];
        const float4* xr = (const float4*)&sXR[d][h * 128];
        const float4* at = (const float4*)&sAtt[h * 128];
        float accv = 0.f;
        #pragma unroll
        for (int c4 = 0; c4 < 32; ++c4) {
            float4 a = xl[c4], b = xr[c4], w = at[c4];
            float e0 = a.x + b.x; e0 = e0 >= 0.f ? e0 : 0.2f * e0;
            float e1 = a.y + b.y; e1 = e1 >= 0.f ? e1 : 0.2f * e1;
            float e2 = a.z + b.z; e2 = e2 >= 0.f ? e2 : 0.2f * e2;
            float e3 = a.w + b.w; e3 = e3 >= 0.f ? e3 : 0.2f * e3;
            accv += w.x * e0 + w.y * e1 + w.z * e2 + w.w * e3;
        }
        sLog[d * 2 + h][s] = accv;
    }
    __syncthreads();

    if (tid < 32) {
        float m = -1e30f;
        #pragma unroll
        for (int s = 0; s < 16; ++s) m = fmaxf(m, sLog[tid][s]);
        float den = 0.f;
        #pragma unroll
        for (int s = 0; s < 16; ++s) {
            float e = expf(sLog[tid][s] - m);
            sLog[tid][s] = e;
            den += e;
        }
        float inv = 1.0f / den;
        #pragma unroll
        for (int s = 0; s < 16; ++s) sLog[tid][s] *= inv;
    }
    __syncthreads();

    int c = tid & 127;
    int db = tid >> 7;
    #pragma unroll
    for (int i = 0; i < 8; ++i) {
        int d = db + 2 * i;
        float accv = 0.f;
        #pragma unroll
        for (int h = 0; h < 2; ++h) {
            const float* al = sLog[d * 2 + h];
            #pragma unroll
            for (int s = 0; s < 16; ++s)
                accv += al[s] * sXL[s][h * 128 + c];
        }
        Xout[(size_t)(base + d) * 128 + c] = 0.5f * accv + sBias[c];
    }
}

// ---------------------------------------------------------------------------
// Gate dot + segment softmax + pooling.
// ---------------------------------------------------------------------------
__global__ __launch_bounds__(256)
void gate_pool(const float* __restrict__ X2, const float* __restrict__ H2,
               const float* __restrict__ gW3, const float* __restrict__ gb3,
               float* __restrict__ out) {
    int mol = blockIdx.x;
    int tid = threadIdx.x;
    __shared__ float sW3[256];
    __shared__ float sg[16];
    __shared__ float ssc[16];

    sW3[tid] = gW3[tid];
    __syncthreads();

    int j = tid >> 4;
    int lane = tid & 15;
    const float* h2 = H2 + (size_t)(mol * 16 + j) * 256;
    float p = 0.f;
    #pragma unroll
    for (int c = lane; c < 256; c += 16) p += h2[c] * sW3[c];
    #pragma unroll
    for (int off = 8; off; off >>= 1) p += __shfl_down(p, off, 16);
    if (lane == 0) sg[j] = p + gb3[0];
    __syncthreads();

    if (tid < 16) {
        float m = -1e30f;
        #pragma unroll
        for (int s = 0; s < 16; ++s) m = fmaxf(m, sg[s]);
        float e = expf(sg[tid] - m);
        float den = e;
        #pragma unroll
        for (int off = 8; off; off >>= 1) den += __shfl_xor(den, off, 16);
        float sc = e / den;
        ssc[tid] = sc;
        out[131072 + mol * 16 + tid] = sc;
    }
    __syncthreads();

    if (tid < 128) {
        const float* xb = X2 + (size_t)(mol * 16) * 128;
        float accv = 0.f;
        #pragma unroll
        for (int s = 0; s < 16; ++s) accv += ssc[s] * xb[s * 128 + tid];
        out[mol * 128 + tid] = accv;
    }
}

// ---------------------------------------------------------------------------
extern "C" void kernel_launch(void* const* d_in, const int* in_sizes, int n_in,
                              void* d_out, int out_size, void* d_ws, size_t ws_size,
                              hipStream_t stream) {
    (void)in_sizes; (void)n_in; (void)out_size; (void)ws_size;
    const float* H        = (const float*)d_in[0];
    const float* Wl       = (const float*)d_in[4];
    const float* bl       = (const float*)d_in[5];
    const float* Wr       = (const float*)d_in[6];
    const float* br       = (const float*)d_in[7];
    const float* att      = (const float*)d_in[8];
    const float* gat_bias = (const float*)d_in[9];
    const float* gW1      = (const float*)d_in[10];
    const float* gb1      = (const float*)d_in[11];
    const float* gW2      = (const float*)d_in[12];
    const float* gb2      = (const float*)d_in[13];
    const float* gW3      = (const float*)d_in[14];
    const float* gb3      = (const float*)d_in[15];
    float* out = (float*)d_out;

    float* A  = (float*)d_ws;                        // [N,256]
    float* Bb = A + (size_t)N_NODES * 256;           // [N,256]
    float* X  = Bb + (size_t)N_NODES * 256;          // [N,128]
    unsigned short* wt = (unsigned short*)(X + (size_t)N_NODES * 128);

    // bf16 hi/lo transposed weights (elem offsets into wt)
    const size_t oWl0 = 0, oWr0 = 65536, oWl1 = 131072, oWr1 = 196608,
                 oG1 = 262144, oG2 = 327680;

    conv_wt<<<896, 256, 0, stream>>>(Wl, Wr, gW1, gW2, wt);

    dim3 fusedGrid(N_NODES / 64, 4);   // xl (2 col tiles) + xr (2 col tiles)
    dim3 mlpGrid(N_NODES / 64, 2);

    // ---- layer 0 ----
    gemm_mfma<<<fusedGrid, 256, 0, stream>>>(H,
        wt + oWl0, wt + oWl0 + 32768, bl, A,
        wt + oWr0, wt + oWr0 + 32768, br, Bb,
        128, 256, 2, 0, 0.f);
    gat_attn<<<B_MOL, 256, 0, stream>>>(A, Bb, att, gat_bias, X);

    // ---- layer 1 ----
    gemm_mfma<<<fusedGrid, 256, 0, stream>>>(X,
        wt + oWl1, wt + oWl1 + 32768, bl + 256, A,
        wt + oWr1, wt + oWr1 + 32768, br + 256, Bb,
        128, 256, 2, 0, 0.f);
    gat_attn<<<B_MOL, 256, 0, stream>>>(A, Bb, att + 256, gat_bias + 128, X);

    // ---- gate MLP ----
    gemm_mfma<<<mlpGrid, 256, 0, stream>>>(X,
        wt + oG1, wt + oG1 + 32768, gb1, A,
        wt + oG1, wt + oG1 + 32768, gb1, A,
        128, 256, 2, 1, 0.01f);
    gemm_mfma<<<mlpGrid, 256, 0, stream>>>(A,
        wt + oG2, wt + oG2 + 65536, gb2, Bb,
        wt + oG2, wt + oG2 + 65536, gb2, Bb,
        256, 256, 2, 1, 0.01f);

    // ---- gate + softmax + pool ----
    gate_pool<<<B_MOL, 256, 0, stream>>>(X, Bb, gW3, gb3, out);
}

// Round 4
// 110.841 us; speedup vs baseline: 1.9493x; 1.3885x over previous
//
#include <hip/hip_runtime.h>
#include <hip/hip_bf16.h>
#include <math.h>

#define N_NODES 16384
#define B_MOL   1024
#define K_CONF  16
#define C_DIM   128
#define HID_DIM 256

typedef __attribute__((ext_vector_type(8))) short short8v;
typedef __attribute__((ext_vector_type(4))) float f32x4;

static __device__ __forceinline__ unsigned short f2bf(float f) {
    unsigned int u = __float_as_uint(f);
    unsigned int r = (u + 0x7FFFu + ((u >> 16) & 1u)) >> 16;   // RNE
    return (unsigned short)r;
}
static __device__ __forceinline__ float bf2f(unsigned short h) {
    return __uint_as_float(((unsigned int)h) << 16);
}

// ---------------------------------------------------------------------------
// Weight convert: W[k][m] fp32 -> Wt[m][k] bf16 hi (at dst) + lo (at dst+256*K).
// ---------------------------------------------------------------------------
__global__ __launch_bounds__(256)
void conv_wt(const float* __restrict__ Wl, const float* __restrict__ Wr,
             const float* __restrict__ g1, const float* __restrict__ g2,
             unsigned short* __restrict__ wt) {
    int idx = blockIdx.x * 256 + threadIdx.x;
    const float* src; int K; size_t dst; int e;
    if      (idx <  32768) { src = Wl;         K = 128; dst = 0;      e = idx;          }
    else if (idx <  65536) { src = Wr;         K = 128; dst = 65536;  e = idx - 32768;  }
    else if (idx <  98304) { src = Wl + 32768; K = 128; dst = 131072; e = idx - 65536;  }
    else if (idx < 131072) { src = Wr + 32768; K = 128; dst = 196608; e = idx - 98304;  }
    else if (idx < 163840) { src = g1;         K = 128; dst = 262144; e = idx - 131072; }
    else if (idx < 229376) { src = g2;         K = 256; dst = 327680; e = idx - 163840; }
    else return;
    int k = e >> 8, m = e & 255;                   // M == 256 for all segments
    float v = src[e];
    unsigned short h = f2bf(v);
    unsigned short l = f2bf(v - bf2f(h));
    wt[dst + (size_t)m * K + k] = h;
    wt[dst + ((size_t)K << 8) + (size_t)m * K + k] = l;
}

// ---------------------------------------------------------------------------
// Split-bf16 MFMA GEMM: Y = act(X @ W + b). BM=64, BN=128, BK=32, 4 waves.
// ---------------------------------------------------------------------------
__global__ __launch_bounds__(256)
void gemm_mfma(const float* __restrict__ X,
               const unsigned short* __restrict__ WAh, const unsigned short* __restrict__ WAl,
               const float* __restrict__ bA, float* __restrict__ YA,
               const unsigned short* __restrict__ WBh, const unsigned short* __restrict__ WBl,
               const float* __restrict__ bB, float* __restrict__ YB,
               int K, int M, int halfTiles, int act, float slope) {
    __shared__ short Ah[64][40], Al[64][40];     // [row][k], pad 40 (80B = 20 banks)
    __shared__ short Bh[128][40], Bl[128][40];   // [col][k]

    int tid = threadIdx.x;
    int rowBase = blockIdx.x * 64;

    const unsigned short *Wh, *Wlo; const float* bias; float* Y; int colBase;
    if ((int)blockIdx.y < halfTiles) {
        Wh = WAh; Wlo = WAl; bias = bA; Y = YA; colBase = blockIdx.y * 128;
    } else {
        Wh = WBh; Wlo = WBl; bias = bB; Y = YB; colBase = (blockIdx.y - halfTiles) * 128;
    }

    int lane = tid & 63;
    int wid  = tid >> 6;
    int wy = wid & 1, wx = wid >> 1;   // 2x2 waves
    int lr = lane & 15;
    int kb = (lane >> 4) * 8;

    f32x4 acc[2][4];
    #pragma unroll
    for (int i = 0; i < 2; ++i)
        #pragma unroll
        for (int j = 0; j < 4; ++j)
            acc[i][j] = (f32x4){0.f, 0.f, 0.f, 0.f};

    for (int kt = 0; kt < K; kt += 32) {
        #pragma unroll
        for (int it = 0; it < 2; ++it) {
            int idx = tid + it * 256;
            int r = idx >> 3, q = idx & 7;
            float4 v = *(const float4*)&X[(size_t)(rowBase + r) * K + kt + q * 4];
            unsigned short h0 = f2bf(v.x), h1 = f2bf(v.y), h2 = f2bf(v.z), h3 = f2bf(v.w);
            *(short4*)&Ah[r][q * 4] = make_short4((short)h0, (short)h1, (short)h2, (short)h3);
            unsigned short l0 = f2bf(v.x - bf2f(h0)), l1 = f2bf(v.y - bf2f(h1));
            unsigned short l2 = f2bf(v.z - bf2f(h2)), l3 = f2bf(v.w - bf2f(h3));
            *(short4*)&Al[r][q * 4] = make_short4((short)l0, (short)l1, (short)l2, (short)l3);
        }
        #pragma unroll
        for (int it = 0; it < 2; ++it) {
            int idx = tid + it * 256;
            int c = idx >> 2, q = idx & 3;
            size_t off = (size_t)(colBase + c) * K + kt + q * 8;
            *(short8v*)&Bh[c][q * 8] = *(const short8v*)&Wh[off];
            *(short8v*)&Bl[c][q * 8] = *(const short8v*)&Wlo[off];
        }
        __syncthreads();

        short8v a_h[2], a_l[2], b_h[4], b_l[4];
        #pragma unroll
        for (int i = 0; i < 2; ++i) {
            a_h[i] = *(const short8v*)&Ah[wy * 32 + i * 16 + lr][kb];
            a_l[i] = *(const short8v*)&Al[wy * 32 + i * 16 + lr][kb];
        }
        #pragma unroll
        for (int j = 0; j < 4; ++j) {
            b_h[j] = *(const short8v*)&Bh[wx * 64 + j * 16 + lr][kb];
            b_l[j] = *(const short8v*)&Bl[wx * 64 + j * 16 + lr][kb];
        }
        #pragma unroll
        for (int i = 0; i < 2; ++i)
            #pragma unroll
            for (int j = 0; j < 4; ++j) {
                acc[i][j] = __builtin_amdgcn_mfma_f32_16x16x32_bf16(a_h[i], b_h[j], acc[i][j], 0, 0, 0);
                acc[i][j] = __builtin_amdgcn_mfma_f32_16x16x32_bf16(a_h[i], b_l[j], acc[i][j], 0, 0, 0);
                acc[i][j] = __builtin_amdgcn_mfma_f32_16x16x32_bf16(a_l[i], b_h[j], acc[i][j], 0, 0, 0);
            }
        __syncthreads();
    }

    #pragma unroll
    for (int i = 0; i < 2; ++i) {
        int row0 = rowBase + wy * 32 + i * 16 + (lane >> 4) * 4;
        #pragma unroll
        for (int j = 0; j < 4; ++j) {
            int colL = colBase + wx * 64 + j * 16 + lr;
            float bv = bias[colL];
            #pragma unroll
            for (int rr = 0; rr < 4; ++rr) {
                float v = acc[i][j][rr] + bv;
                if (act) v = v >= 0.f ? v : slope * v;
                Y[(size_t)(row0 + rr) * M + colL] = v;
            }
        }
    }
}

// ---------------------------------------------------------------------------
// GATv2 attention, restructured: only XL staged in LDS; att/xr in registers;
// leaky(x,0.2) = 0.6x + 0.4|x|; shfl-reduce over channel chunks.
// Thread map P1: tid = dh*8 + cq  (dh = d*2+h in 0..31, cq = 0..7, 16 ch each)
// Thread map P3: tid = doo*32 + c4 (doo = 0..7 -> rows doo, doo+8; c4 = 0..31)
// ---------------------------------------------------------------------------
__global__ __launch_bounds__(256)
void gat_attn(const float* __restrict__ XL, const float* __restrict__ XR,
              const float* __restrict__ att, const float* __restrict__ gbias,
              float* __restrict__ Xout) {
    int mol = blockIdx.x;
    int tid = threadIdx.x;
    __shared__ float sXL[16][260];   // row-internal accesses only
    __shared__ float sLog[32][20];   // logits -> alphas; 80B rows (16B aligned)

    int base = mol * 16;
    {
        const float4* src = (const float4*)(XL + (size_t)base * 256);
        #pragma unroll
        for (int it = 0; it < 4; ++it) {
            int i = tid + it * 256;
            int node = i >> 6, c4 = i & 63;
            *(float4*)&sXL[node][c4 * 4] = src[(size_t)node * 64 + c4];
        }
    }

    int dh = tid >> 3;          // d*2 + h
    int cq = tid & 7;           // 16-channel chunk
    int d  = dh >> 1, h = dh & 1;

    float4 a6[4], a4[4], xr4[4];
    {
        const float4* ap = (const float4*)(att + h * 128 + cq * 16);
        const float4* xp = (const float4*)(XR + (size_t)(base + d) * 256 + h * 128 + cq * 16);
        #pragma unroll
        for (int q = 0; q < 4; ++q) {
            float4 a = ap[q];
            a6[q] = make_float4(0.6f * a.x, 0.6f * a.y, 0.6f * a.z, 0.6f * a.w);
            a4[q] = make_float4(0.4f * a.x, 0.4f * a.y, 0.4f * a.z, 0.4f * a.w);
            xr4[q] = xp[q];
        }
    }
    __syncthreads();

    // ---- phase 1: logits[dh][s] ----
    #pragma unroll 4
    for (int s = 0; s < 16; ++s) {
        const float4* xl = (const float4*)&sXL[s][h * 128 + cq * 16];
        float acc = 0.f;
        #pragma unroll
        for (int q = 0; q < 4; ++q) {
            float4 x = xl[q];
            float e0 = x.x + xr4[q].x;
            float e1 = x.y + xr4[q].y;
            float e2 = x.z + xr4[q].z;
            float e3 = x.w + xr4[q].w;
            acc += a6[q].x * e0 + a4[q].x * fabsf(e0);
            acc += a6[q].y * e1 + a4[q].y * fabsf(e1);
            acc += a6[q].z * e2 + a4[q].z * fabsf(e2);
            acc += a6[q].w * e3 + a4[q].w * fabsf(e3);
        }
        acc += __shfl_down(acc, 4);
        acc += __shfl_down(acc, 2);
        acc += __shfl_down(acc, 1);
        if (cq == 0) sLog[dh][s] = acc;
    }
    __syncthreads();

    // ---- phase 2: softmax over s per (d,h) ----
    if (tid < 32) {
        float v[16];
        float m = -1e30f;
        #pragma unroll
        for (int s = 0; s < 16; ++s) { v[s] = sLog[tid][s]; m = fmaxf(m, v[s]); }
        float den = 0.f;
        #pragma unroll
        for (int s = 0; s < 16; ++s) { v[s] = expf(v[s] - m); den += v[s]; }
        float inv = 1.0f / den;
        #pragma unroll
        for (int s = 0; s < 16; ++s) sLog[tid][s] = v[s] * inv;
    }
    __syncthreads();

    // ---- phase 3: out[d][c] = 0.5 * sum_{h,s} alpha * xl + bias ----
    int doo = tid >> 5;          // output rows doo and doo+8
    int c4b = (tid & 31) * 4;    // channel base
    float4 acc0 = make_float4(0.f, 0.f, 0.f, 0.f);
    float4 acc1 = make_float4(0.f, 0.f, 0.f, 0.f);

    #pragma unroll
    for (int hh = 0; hh < 2; ++hh) {
        const float4* ar0 = (const float4*)&sLog[(doo    ) * 2 + hh][0];
        const float4* ar1 = (const float4*)&sLog[(doo + 8) * 2 + hh][0];
        #pragma unroll
        for (int sq = 0; sq < 4; ++sq) {
            float4 A0 = ar0[sq];
            float4 A1 = ar1[sq];
            float4 x;
            x = *(const float4*)&sXL[sq * 4 + 0][hh * 128 + c4b];
            acc0.x += A0.x * x.x; acc0.y += A0.x * x.y; acc0.z += A0.x * x.z; acc0.w += A0.x * x.w;
            acc1.x += A1.x * x.x; acc1.y += A1.x * x.y; acc1.z += A1.x * x.z; acc1.w += A1.x * x.w;
            x = *(const float4*)&sXL[sq * 4 + 1][hh * 128 + c4b];
            acc0.x += A0.y * x.x; acc0.y += A0.y * x.y; acc0.z += A0.y * x.z; acc0.w += A0.y * x.w;
            acc1.x += A1.y * x.x; acc1.y += A1.y * x.y; acc1.z += A1.y * x.z; acc1.w += A1.y * x.w;
            x = *(const float4*)&sXL[sq * 4 + 2][hh * 128 + c4b];
            acc0.x += A0.z * x.x; acc0.y += A0.z * x.y; acc0.z += A0.z * x.z; acc0.w += A0.z * x.w;
            acc1.x += A1.z * x.x; acc1.y += A1.z * x.y; acc1.z += A1.z * x.z; acc1.w += A1.z * x.w;
            x = *(const float4*)&sXL[sq * 4 + 3][hh * 128 + c4b];
            acc0.x += A0.w * x.x; acc0.y += A0.w * x.y; acc0.z += A0.w * x.z; acc0.w += A0.w * x.w;
            acc1.x += A1.w * x.x; acc1.y += A1.w * x.y; acc1.z += A1.w * x.z; acc1.w += A1.w * x.w;
        }
    }

    float4 bv = *(const float4*)&gbias[c4b];
    float4 o0 = make_float4(0.5f * acc0.x + bv.x, 0.5f * acc0.y + bv.y,
                            0.5f * acc0.z + bv.z, 0.5f * acc0.w + bv.w);
    float4 o1 = make_float4(0.5f * acc1.x + bv.x, 0.5f * acc1.y + bv.y,
                            0.5f * acc1.z + bv.z, 0.5f * acc1.w + bv.w);
    *(float4*)&Xout[(size_t)(base + doo    ) * 128 + c4b] = o0;
    *(float4*)&Xout[(size_t)(base + doo + 8) * 128 + c4b] = o1;
}

// ---------------------------------------------------------------------------
// Gate dot + segment softmax + pooling.
// ---------------------------------------------------------------------------
__global__ __launch_bounds__(256)
void gate_pool(const float* __restrict__ X2, const float* __restrict__ H2,
               const float* __restrict__ gW3, const float* __restrict__ gb3,
               float* __restrict__ out) {
    int mol = blockIdx.x;
    int tid = threadIdx.x;
    __shared__ float sW3[256];
    __shared__ float sg[16];
    __shared__ float ssc[16];

    sW3[tid] = gW3[tid];
    __syncthreads();

    int j = tid >> 4;
    int lane = tid & 15;
    const float* h2 = H2 + (size_t)(mol * 16 + j) * 256;
    float p = 0.f;
    #pragma unroll
    for (int c = lane; c < 256; c += 16) p += h2[c] * sW3[c];
    #pragma unroll
    for (int off = 8; off; off >>= 1) p += __shfl_down(p, off, 16);
    if (lane == 0) sg[j] = p + gb3[0];
    __syncthreads();

    if (tid < 16) {
        float m = -1e30f;
        #pragma unroll
        for (int s = 0; s < 16; ++s) m = fmaxf(m, sg[s]);
        float e = expf(sg[tid] - m);
        float den = e;
        #pragma unroll
        for (int off = 8; off; off >>= 1) den += __shfl_xor(den, off, 16);
        float sc = e / den;
        ssc[tid] = sc;
        out[131072 + mol * 16 + tid] = sc;
    }
    __syncthreads();

    if (tid < 128) {
        const float* xb = X2 + (size_t)(mol * 16) * 128;
        float accv = 0.f;
        #pragma unroll
        for (int s = 0; s < 16; ++s) accv += ssc[s] * xb[s * 128 + tid];
        out[mol * 128 + tid] = accv;
    }
}

// ---------------------------------------------------------------------------
extern "C" void kernel_launch(void* const* d_in, const int* in_sizes, int n_in,
                              void* d_out, int out_size, void* d_ws, size_t ws_size,
                              hipStream_t stream) {
    (void)in_sizes; (void)n_in; (void)out_size; (void)ws_size;
    const float* H        = (const float*)d_in[0];
    const float* Wl       = (const float*)d_in[4];
    const float* bl       = (const float*)d_in[5];
    const float* Wr       = (const float*)d_in[6];
    const float* br       = (const float*)d_in[7];
    const float* att      = (const float*)d_in[8];
    const float* gat_bias = (const float*)d_in[9];
    const float* gW1      = (const float*)d_in[10];
    const float* gb1      = (const float*)d_in[11];
    const float* gW2      = (const float*)d_in[12];
    const float* gb2      = (const float*)d_in[13];
    const float* gW3      = (const float*)d_in[14];
    const float* gb3      = (const float*)d_in[15];
    float* out = (float*)d_out;

    float* A  = (float*)d_ws;                        // [N,256]
    float* Bb = A + (size_t)N_NODES * 256;           // [N,256]
    float* X  = Bb + (size_t)N_NODES * 256;          // [N,128]
    unsigned short* wt = (unsigned short*)(X + (size_t)N_NODES * 128);

    const size_t oWl0 = 0, oWr0 = 65536, oWl1 = 131072, oWr1 = 196608,
                 oG1 = 262144, oG2 = 327680;

    conv_wt<<<896, 256, 0, stream>>>(Wl, Wr, gW1, gW2, wt);

    dim3 fusedGrid(N_NODES / 64, 4);
    dim3 mlpGrid(N_NODES / 64, 2);

    // ---- layer 0 ----
    gemm_mfma<<<fusedGrid, 256, 0, stream>>>(H,
        wt + oWl0, wt + oWl0 + 32768, bl, A,
        wt + oWr0, wt + oWr0 + 32768, br, Bb,
        128, 256, 2, 0, 0.f);
    gat_attn<<<B_MOL, 256, 0, stream>>>(A, Bb, att, gat_bias, X);

    // ---- layer 1 ----
    gemm_mfma<<<fusedGrid, 256, 0, stream>>>(X,
        wt + oWl1, wt + oWl1 + 32768, bl + 256, A,
        wt + oWr1, wt + oWr1 + 32768, br + 256, Bb,
        128, 256, 2, 0, 0.f);
    gat_attn<<<B_MOL, 256, 0, stream>>>(A, Bb, att + 256, gat_bias + 128, X);

    // ---- gate MLP ----
    gemm_mfma<<<mlpGrid, 256, 0, stream>>>(X,
        wt + oG1, wt + oG1 + 32768, gb1, A,
        wt + oG1, wt + oG1 + 32768, gb1, A,
        128, 256, 2, 1, 0.01f);
    gemm_mfma<<<mlpGrid, 256, 0, stream>>>(A,
        wt + oG2, wt + oG2 + 65536, gb2, Bb,
        wt + oG2, wt + oG2 + 65536, gb2, Bb,
        256, 256, 2, 1, 0.01f);

    // ---- gate + softmax + pool ----
    gate_pool<<<B_MOL, 256, 0, stream>>>(X, Bb, gW3, gb3, out);
}

// Round 5
// 109.140 us; speedup vs baseline: 1.9797x; 1.0156x over previous
//
#include <hip/hip_runtime.h>
#include <hip/hip_bf16.h>
#include <math.h>

#define N_NODES 16384
#define B_MOL   1024
#define K_CONF  16
#define C_DIM   128
#define HID_DIM 256

typedef __attribute__((ext_vector_type(8))) short short8v;
typedef __attribute__((ext_vector_type(4))) float f32x4;

static __device__ __forceinline__ unsigned short f2bf(float f) {
    unsigned int u = __float_as_uint(f);
    unsigned int r = (u + 0x7FFFu + ((u >> 16) & 1u)) >> 16;   // RNE
    return (unsigned short)r;
}
static __device__ __forceinline__ float bf2f(unsigned short h) {
    return __uint_as_float(((unsigned int)h) << 16);
}

// ---------------------------------------------------------------------------
// Convert weights (to transposed bf16 hi/lo) and H (to bf16 hi/lo, row-major).
// Weight segments enumerated DEST-major: e = m*K + k -> contiguous stores.
// wt layout per segment: hi at dst+e, lo at dst + K*256 + e.
// ---------------------------------------------------------------------------
__global__ __launch_bounds__(256)
void conv_all(const float* __restrict__ Wl, const float* __restrict__ Wr,
              const float* __restrict__ g1, const float* __restrict__ g2,
              const float* __restrict__ H,
              unsigned short* __restrict__ wt,
              unsigned short* __restrict__ Hh, unsigned short* __restrict__ Hl) {
    int idx = blockIdx.x * 256 + threadIdx.x;
    if (idx < 229376) {
        const float* src; int sh; size_t dst; int e;
        if      (idx <  32768) { src = Wl;         sh = 7; dst = 0;      e = idx;          }
        else if (idx <  65536) { src = Wr;         sh = 7; dst = 65536;  e = idx - 32768;  }
        else if (idx <  98304) { src = Wl + 32768; sh = 7; dst = 131072; e = idx - 65536;  }
        else if (idx < 131072) { src = Wr + 32768; sh = 7; dst = 196608; e = idx - 98304;  }
        else if (idx < 163840) { src = g1;         sh = 7; dst = 262144; e = idx - 131072; }
        else                   { src = g2;         sh = 8; dst = 327680; e = idx - 163840; }
        int Kd = 1 << sh;
        int m = e >> sh, k = e & (Kd - 1);
        float v = src[(size_t)k * 256 + m];
        unsigned short h = f2bf(v);
        wt[dst + e] = h;
        wt[dst + ((size_t)Kd << 8) + e] = f2bf(v - bf2f(h));
    } else {
        int e = idx - 229376;   // < 2097152
        float v = H[e];
        unsigned short h = f2bf(v);
        Hh[e] = h;
        Hl[e] = f2bf(v - bf2f(h));
    }
}

// ---------------------------------------------------------------------------
// Split-bf16 MFMA GEMM, activations pre-split. BM=BN=128, BK=32, 8 waves
// (4x2), wave tile 32x64 = 2x4 frags of 16x16x32. Dual-output via halfTiles.
// OM=0: fp32 out. OM=1: bf16 hi/lo out (after bias+act).
// ---------------------------------------------------------------------------
template<int OM>
__global__ __launch_bounds__(512, 4)
void gemm_bf16(const unsigned short* __restrict__ Xh, const unsigned short* __restrict__ Xl,
               const unsigned short* __restrict__ WAh, const unsigned short* __restrict__ WAl,
               const float* __restrict__ bA, float* __restrict__ YAf,
               unsigned short* __restrict__ YAh, unsigned short* __restrict__ YAl,
               const unsigned short* __restrict__ WBh, const unsigned short* __restrict__ WBl,
               const float* __restrict__ bB, float* __restrict__ YBf,
               unsigned short* __restrict__ YBh, unsigned short* __restrict__ YBl,
               int K, int M, int halfTiles, int act, float slope) {
    __shared__ short Ah[128][40], Al[128][40];   // [row][k], pad 40 (80B = 20 banks)
    __shared__ short Bh[128][40], Bl[128][40];   // [col][k]

    int tid = threadIdx.x;
    int rowBase = blockIdx.x * 128;

    const unsigned short *Wh, *Wlo; const float* bias;
    float* Yf; unsigned short *Yh, *Yl; int colBase;
    if ((int)blockIdx.y < halfTiles) {
        Wh = WAh; Wlo = WAl; bias = bA; Yf = YAf; Yh = YAh; Yl = YAl;
        colBase = blockIdx.y * 128;
    } else {
        Wh = WBh; Wlo = WBl; bias = bB; Yf = YBf; Yh = YBh; Yl = YBl;
        colBase = (blockIdx.y - halfTiles) * 128;
    }

    int lane = tid & 63;
    int wid  = tid >> 6;
    int wy = wid & 3, wx = wid >> 2;   // 4x2 waves, wave tile 32x64
    int lr = lane & 15;
    int kb = (lane >> 4) * 8;

    int sr = tid >> 2;                 // staging row/col (0..127)
    int sq = (tid & 3) * 8;            // staging k-offset (shorts)

    f32x4 acc[2][4];
    #pragma unroll
    for (int i = 0; i < 2; ++i)
        #pragma unroll
        for (int j = 0; j < 4; ++j)
            acc[i][j] = (f32x4){0.f, 0.f, 0.f, 0.f};

    for (int kt = 0; kt < K; kt += 32) {
        size_t aoff = (size_t)(rowBase + sr) * K + kt + sq;
        size_t boff = (size_t)(colBase + sr) * K + kt + sq;
        *(short8v*)&Ah[sr][sq] = *(const short8v*)&Xh[aoff];
        *(short8v*)&Al[sr][sq] = *(const short8v*)&Xl[aoff];
        *(short8v*)&Bh[sr][sq] = *(const short8v*)&Wh[boff];
        *(short8v*)&Bl[sr][sq] = *(const short8v*)&Wlo[boff];
        __syncthreads();

        short8v a_h[2], a_l[2], b_h[4], b_l[4];
        #pragma unroll
        for (int i = 0; i < 2; ++i) {
            a_h[i] = *(const short8v*)&Ah[wy * 32 + i * 16 + lr][kb];
            a_l[i] = *(const short8v*)&Al[wy * 32 + i * 16 + lr][kb];
        }
        #pragma unroll
        for (int j = 0; j < 4; ++j) {
            b_h[j] = *(const short8v*)&Bh[wx * 64 + j * 16 + lr][kb];
            b_l[j] = *(const short8v*)&Bl[wx * 64 + j * 16 + lr][kb];
        }
        #pragma unroll
        for (int i = 0; i < 2; ++i)
            #pragma unroll
            for (int j = 0; j < 4; ++j) {
                acc[i][j] = __builtin_amdgcn_mfma_f32_16x16x32_bf16(a_h[i], b_h[j], acc[i][j], 0, 0, 0);
                acc[i][j] = __builtin_amdgcn_mfma_f32_16x16x32_bf16(a_h[i], b_l[j], acc[i][j], 0, 0, 0);
                acc[i][j] = __builtin_amdgcn_mfma_f32_16x16x32_bf16(a_l[i], b_h[j], acc[i][j], 0, 0, 0);
            }
        __syncthreads();
    }

    #pragma unroll
    for (int i = 0; i < 2; ++i) {
        int row0 = rowBase + wy * 32 + i * 16 + (lane >> 4) * 4;
        #pragma unroll
        for (int j = 0; j < 4; ++j) {
            int colL = colBase + wx * 64 + j * 16 + lr;
            float bv = bias[colL];
            #pragma unroll
            for (int rr = 0; rr < 4; ++rr) {
                float v = acc[i][j][rr] + bv;
                if (act) v = v >= 0.f ? v : slope * v;
                size_t off = (size_t)(row0 + rr) * M + colL;
                if (OM == 0) {
                    Yf[off] = v;
                } else {
                    unsigned short h = f2bf(v);
                    Yh[off] = h;
                    Yl[off] = f2bf(v - bf2f(h));
                }
            }
        }
    }
}

// ---------------------------------------------------------------------------
// GATv2 attention per 16-node molecule. Outputs fp32 X (optional) and
// bf16 hi/lo X (for downstream GEMMs).
// ---------------------------------------------------------------------------
__global__ __launch_bounds__(256)
void gat_attn(const float* __restrict__ XL, const float* __restrict__ XR,
              const float* __restrict__ att, const float* __restrict__ gbias,
              float* __restrict__ XoutF,
              unsigned short* __restrict__ Xoh, unsigned short* __restrict__ Xol) {
    int mol = blockIdx.x;
    int tid = threadIdx.x;
    __shared__ float sXL[16][260];
    __shared__ float sLog[32][20];

    int base = mol * 16;
    {
        const float4* src = (const float4*)(XL + (size_t)base * 256);
        #pragma unroll
        for (int it = 0; it < 4; ++it) {
            int i = tid + it * 256;
            int node = i >> 6, c4 = i & 63;
            *(float4*)&sXL[node][c4 * 4] = src[(size_t)node * 64 + c4];
        }
    }

    int dh = tid >> 3;
    int cq = tid & 7;
    int d  = dh >> 1, h = dh & 1;

    float4 a6[4], a4[4], xr4[4];
    {
        const float4* ap = (const float4*)(att + h * 128 + cq * 16);
        const float4* xp = (const float4*)(XR + (size_t)(base + d) * 256 + h * 128 + cq * 16);
        #pragma unroll
        for (int q = 0; q < 4; ++q) {
            float4 a = ap[q];
            a6[q] = make_float4(0.6f * a.x, 0.6f * a.y, 0.6f * a.z, 0.6f * a.w);
            a4[q] = make_float4(0.4f * a.x, 0.4f * a.y, 0.4f * a.z, 0.4f * a.w);
            xr4[q] = xp[q];
        }
    }
    __syncthreads();

    #pragma unroll 4
    for (int s = 0; s < 16; ++s) {
        const float4* xl = (const float4*)&sXL[s][h * 128 + cq * 16];
        float acc = 0.f;
        #pragma unroll
        for (int q = 0; q < 4; ++q) {
            float4 x = xl[q];
            float e0 = x.x + xr4[q].x;
            float e1 = x.y + xr4[q].y;
            float e2 = x.z + xr4[q].z;
            float e3 = x.w + xr4[q].w;
            acc += a6[q].x * e0 + a4[q].x * fabsf(e0);
            acc += a6[q].y * e1 + a4[q].y * fabsf(e1);
            acc += a6[q].z * e2 + a4[q].z * fabsf(e2);
            acc += a6[q].w * e3 + a4[q].w * fabsf(e3);
        }
        acc += __shfl_down(acc, 4);
        acc += __shfl_down(acc, 2);
        acc += __shfl_down(acc, 1);
        if (cq == 0) sLog[dh][s] = acc;
    }
    __syncthreads();

    if (tid < 32) {
        float v[16];
        float m = -1e30f;
        #pragma unroll
        for (int s = 0; s < 16; ++s) { v[s] = sLog[tid][s]; m = fmaxf(m, v[s]); }
        float den = 0.f;
        #pragma unroll
        for (int s = 0; s < 16; ++s) { v[s] = expf(v[s] - m); den += v[s]; }
        float inv = 1.0f / den;
        #pragma unroll
        for (int s = 0; s < 16; ++s) sLog[tid][s] = v[s] * inv;
    }
    __syncthreads();

    int doo = tid >> 5;
    int c4b = (tid & 31) * 4;
    float4 acc0 = make_float4(0.f, 0.f, 0.f, 0.f);
    float4 acc1 = make_float4(0.f, 0.f, 0.f, 0.f);

    #pragma unroll
    for (int hh = 0; hh < 2; ++hh) {
        const float4* ar0 = (const float4*)&sLog[(doo    ) * 2 + hh][0];
        const float4* ar1 = (const float4*)&sLog[(doo + 8) * 2 + hh][0];
        #pragma unroll
        for (int sq = 0; sq < 4; ++sq) {
            float4 A0 = ar0[sq];
            float4 A1 = ar1[sq];
            float4 x;
            x = *(const float4*)&sXL[sq * 4 + 0][hh * 128 + c4b];
            acc0.x += A0.x * x.x; acc0.y += A0.x * x.y; acc0.z += A0.x * x.z; acc0.w += A0.x * x.w;
            acc1.x += A1.x * x.x; acc1.y += A1.x * x.y; acc1.z += A1.x * x.z; acc1.w += A1.x * x.w;
            x = *(const float4*)&sXL[sq * 4 + 1][hh * 128 + c4b];
            acc0.x += A0.y * x.x; acc0.y += A0.y * x.y; acc0.z += A0.y * x.z; acc0.w += A0.y * x.w;
            acc1.x += A1.y * x.x; acc1.y += A1.y * x.y; acc1.z += A1.y * x.z; acc1.w += A1.y * x.w;
            x = *(const float4*)&sXL[sq * 4 + 2][hh * 128 + c4b];
            acc0.x += A0.z * x.x; acc0.y += A0.z * x.y; acc0.z += A0.z * x.z; acc0.w += A0.z * x.w;
            acc1.x += A1.z * x.x; acc1.y += A1.z * x.y; acc1.z += A1.z * x.z; acc1.w += A1.z * x.w;
            x = *(const float4*)&sXL[sq * 4 + 3][hh * 128 + c4b];
            acc0.x += A0.w * x.x; acc0.y += A0.w * x.y; acc0.z += A0.w * x.z; acc0.w += A0.w * x.w;
            acc1.x += A1.w * x.x; acc1.y += A1.w * x.y; acc1.z += A1.w * x.z; acc1.w += A1.w * x.w;
        }
    }

    float4 bv = *(const float4*)&gbias[c4b];
    float4 o0 = make_float4(0.5f * acc0.x + bv.x, 0.5f * acc0.y + bv.y,
                            0.5f * acc0.z + bv.z, 0.5f * acc0.w + bv.w);
    float4 o1 = make_float4(0.5f * acc1.x + bv.x, 0.5f * acc1.y + bv.y,
                            0.5f * acc1.z + bv.z, 0.5f * acc1.w + bv.w);
    size_t off0 = (size_t)(base + doo    ) * 128 + c4b;
    size_t off1 = (size_t)(base + doo + 8) * 128 + c4b;
    if (XoutF) {
        *(float4*)&XoutF[off0] = o0;
        *(float4*)&XoutF[off1] = o1;
    }
    unsigned short h0 = f2bf(o0.x), h1 = f2bf(o0.y), h2 = f2bf(o0.z), h3 = f2bf(o0.w);
    *(short4*)&Xoh[off0] = make_short4((short)h0, (short)h1, (short)h2, (short)h3);
    *(short4*)&Xol[off0] = make_short4((short)f2bf(o0.x - bf2f(h0)), (short)f2bf(o0.y - bf2f(h1)),
                                       (short)f2bf(o0.z - bf2f(h2)), (short)f2bf(o0.w - bf2f(h3)));
    h0 = f2bf(o1.x); h1 = f2bf(o1.y); h2 = f2bf(o1.z); h3 = f2bf(o1.w);
    *(short4*)&Xoh[off1] = make_short4((short)h0, (short)h1, (short)h2, (short)h3);
    *(short4*)&Xol[off1] = make_short4((short)f2bf(o1.x - bf2f(h0)), (short)f2bf(o1.y - bf2f(h1)),
                                       (short)f2bf(o1.z - bf2f(h2)), (short)f2bf(o1.w - bf2f(h3)));
}

// ---------------------------------------------------------------------------
// Gate dot + segment softmax + pooling.
// ---------------------------------------------------------------------------
__global__ __launch_bounds__(256)
void gate_pool(const float* __restrict__ X2, const float* __restrict__ H2,
               const float* __restrict__ gW3, const float* __restrict__ gb3,
               float* __restrict__ out) {
    int mol = blockIdx.x;
    int tid = threadIdx.x;
    __shared__ float sW3[256];
    __shared__ float sg[16];
    __shared__ float ssc[16];

    sW3[tid] = gW3[tid];
    __syncthreads();

    int j = tid >> 4;
    int lane = tid & 15;
    const float* h2 = H2 + (size_t)(mol * 16 + j) * 256;
    float p = 0.f;
    #pragma unroll
    for (int c = lane; c < 256; c += 16) p += h2[c] * sW3[c];
    #pragma unroll
    for (int off = 8; off; off >>= 1) p += __shfl_down(p, off, 16);
    if (lane == 0) sg[j] = p + gb3[0];
    __syncthreads();

    if (tid < 16) {
        float m = -1e30f;
        #pragma unroll
        for (int s = 0; s < 16; ++s) m = fmaxf(m, sg[s]);
        float e = expf(sg[tid] - m);
        float den = e;
        #pragma unroll
        for (int off = 8; off; off >>= 1) den += __shfl_xor(den, off, 16);
        float sc = e / den;
        ssc[tid] = sc;
        out[131072 + mol * 16 + tid] = sc;
    }
    __syncthreads();

    if (tid < 128) {
        const float* xb = X2 + (size_t)(mol * 16) * 128;
        float accv = 0.f;
        #pragma unroll
        for (int s = 0; s < 16; ++s) accv += ssc[s] * xb[s * 128 + tid];
        out[mol * 128 + tid] = accv;
    }
}

// ---------------------------------------------------------------------------
extern "C" void kernel_launch(void* const* d_in, const int* in_sizes, int n_in,
                              void* d_out, int out_size, void* d_ws, size_t ws_size,
                              hipStream_t stream) {
    (void)in_sizes; (void)n_in; (void)out_size; (void)ws_size;
    const float* H        = (const float*)d_in[0];
    const float* Wl       = (const float*)d_in[4];
    const float* bl       = (const float*)d_in[5];
    const float* Wr       = (const float*)d_in[6];
    const float* br       = (const float*)d_in[7];
    const float* att      = (const float*)d_in[8];
    const float* gat_bias = (const float*)d_in[9];
    const float* gW1      = (const float*)d_in[10];
    const float* gb1      = (const float*)d_in[11];
    const float* gW2      = (const float*)d_in[12];
    const float* gb2      = (const float*)d_in[13];
    const float* gW3      = (const float*)d_in[14];
    const float* gb3      = (const float*)d_in[15];
    float* out = (float*)d_out;

    float* A  = (float*)d_ws;                        // [N,256] fp32
    float* Bb = A + (size_t)N_NODES * 256;           // [N,256] fp32
    float* X  = Bb + (size_t)N_NODES * 256;          // [N,128] fp32 (gat1 out)
    unsigned short* wt  = (unsigned short*)(X + (size_t)N_NODES * 128);
    unsigned short* Hh  = wt  + 458752;              // [N,128]
    unsigned short* Hl  = Hh  + (size_t)N_NODES * 128;
    unsigned short* Xbh = Hl  + (size_t)N_NODES * 128;   // [N,128] shared gat0/gat1
    unsigned short* Xbl = Xbh + (size_t)N_NODES * 128;
    unsigned short* Mh  = Xbl + (size_t)N_NODES * 128;   // [N,256] MLP1 out
    unsigned short* Ml  = Mh  + (size_t)N_NODES * 256;

    const size_t oWl0 = 0, oWr0 = 65536, oWl1 = 131072, oWr1 = 196608,
                 oG1 = 262144, oG2 = 327680;

    conv_all<<<9088, 256, 0, stream>>>(Wl, Wr, gW1, gW2, H, wt, Hh, Hl);

    dim3 fusedGrid(N_NODES / 128, 4);
    dim3 mlpGrid(N_NODES / 128, 2);

    // ---- layer 0: xl -> A, xr -> Bb (fp32) ----
    gemm_bf16<0><<<fusedGrid, 512, 0, stream>>>(Hh, Hl,
        wt + oWl0, wt + oWl0 + 32768, bl, A, nullptr, nullptr,
        wt + oWr0, wt + oWr0 + 32768, br, Bb, nullptr, nullptr,
        128, 256, 2, 0, 0.f);
    gat_attn<<<B_MOL, 256, 0, stream>>>(A, Bb, att, gat_bias, nullptr, Xbh, Xbl);

    // ---- layer 1 ----
    gemm_bf16<0><<<fusedGrid, 512, 0, stream>>>(Xbh, Xbl,
        wt + oWl1, wt + oWl1 + 32768, bl + 256, A, nullptr, nullptr,
        wt + oWr1, wt + oWr1 + 32768, br + 256, Bb, nullptr, nullptr,
        128, 256, 2, 0, 0.f);
    gat_attn<<<B_MOL, 256, 0, stream>>>(A, Bb, att + 256, gat_bias + 128, X, Xbh, Xbl);

    // ---- gate MLP: h1 = leaky(X@gW1+gb1) -> bf16 pair; h2 = leaky(h1@gW2+gb2) -> fp32 ----
    gemm_bf16<1><<<mlpGrid, 512, 0, stream>>>(Xbh, Xbl,
        wt + oG1, wt + oG1 + 32768, gb1, nullptr, Mh, Ml,
        nullptr, nullptr, nullptr, nullptr, nullptr, nullptr,
        128, 256, 2, 1, 0.01f);
    gemm_bf16<0><<<mlpGrid, 512, 0, stream>>>(Mh, Ml,
        wt + oG2, wt + oG2 + 65536, gb2, Bb, nullptr, nullptr,
        nullptr, nullptr, nullptr, nullptr, nullptr, nullptr,
        256, 256, 2, 1, 0.01f);

    // ---- gate + softmax + pool ----
    gate_pool<<<B_MOL, 256, 0, stream>>>(X, Bb, gW3, gb3, out);
}

// Round 6
// 82.462 us; speedup vs baseline: 2.6201x; 1.3235x over previous
//
#include <hip/hip_runtime.h>
#include <hip/hip_bf16.h>
#include <math.h>

#define N_NODES 16384
#define B_MOL   1024

typedef __attribute__((ext_vector_type(8))) short short8v;
typedef __attribute__((ext_vector_type(4))) float f32x4;

static __device__ __forceinline__ unsigned short f2bf(float f) {
    unsigned int u = __float_as_uint(f);
    unsigned int r = (u + 0x7FFFu + ((u >> 16) & 1u)) >> 16;   // RNE
    return (unsigned short)r;
}
static __device__ __forceinline__ float bf2f(unsigned short h) {
    return __uint_as_float(((unsigned int)h) << 16);
}

// ---------------------------------------------------------------------------
// Pack all weights into MFMA-fragment order, bf16 hi/lo.
// Fragment = (colblk of 16 cols) x (kstep of 32 k): 512 shorts, lane-major:
//   lane = (kk>>3)*16 + (col&15), pos = kk&7  ->  wave load = lane*8, coalesced.
// Matrix layout: frag index = (cb*nK + ks)*2 + hl, each 512 shorts.
// Segments (short offsets): L0 (512x128) @0, L1 @131072, M1 (256x128) @262144,
// M2 (256x256) @327680. Total 458752 shorts.
// ---------------------------------------------------------------------------
__global__ __launch_bounds__(256)
void conv_pack(const float* __restrict__ Wl, const float* __restrict__ Wr,
               const float* __restrict__ g1, const float* __restrict__ g2,
               unsigned short* __restrict__ wpk) {
    int idx = blockIdx.x * 256 + threadIdx.x;
    if (idx >= 229376) return;
    float v; size_t base; int nK, k, col;
    if (idx < 131072) {                      // layers 0/1: 512 cols x 128 k
        int l = idx >> 16;
        int e = idx & 65535;
        k = e >> 9; col = e & 511;
        v = (col < 256) ? Wl[l * 32768 + k * 256 + col]
                        : Wr[l * 32768 + k * 256 + (col - 256)];
        base = (size_t)l * 131072; nK = 4;
    } else if (idx < 163840) {               // MLP1: 256 x 128
        int e = idx - 131072; k = e >> 8; col = e & 255;
        v = g1[k * 256 + col]; base = 262144; nK = 4;
    } else {                                 // MLP2: 256 x 256
        int e = idx - 163840; k = e >> 8; col = e & 255;
        v = g2[k * 256 + col]; base = 327680; nK = 8;
    }
    int cb = col >> 4, ci = col & 15, ks = k >> 5, kk = k & 31;
    int lane = ((kk >> 3) << 4) | ci;
    size_t fo = ((size_t)(cb * nK + ks) * 2) * 512 + lane * 8 + (kk & 7);
    unsigned short h = f2bf(v);
    wpk[base + fo] = h;
    wpk[base + fo + 512] = f2bf(v - bf2f(h));
}

// ---------------------------------------------------------------------------
// Wave-tile GEMM: 32 rows x (NCB*16) cols, K = NK*32. A (bf16 hi/lo pairs)
// from LDS [32][264]; B from frag-packed global (register double-buffered).
// Split-bf16: acc += ah*bh + ah*bl + al*bh.
// ---------------------------------------------------------------------------
template<int NK, int NCB>
static __device__ __forceinline__ void tile_gemm(
        const short* __restrict__ Ah, const short* __restrict__ Al,
        const unsigned short* __restrict__ wv,
        f32x4 (&acc)[2][NCB], int lane) {
    int lr = lane & 15;
    int kq = (lane >> 4) * 8;
    short8v bc[NCB][2], bn[NCB][2];
    #pragma unroll
    for (int j = 0; j < NCB; ++j) {
        bc[j][0] = *(const short8v*)&wv[((j * NK + 0) * 2 + 0) * 512 + lane * 8];
        bc[j][1] = *(const short8v*)&wv[((j * NK + 0) * 2 + 1) * 512 + lane * 8];
    }
    #pragma unroll
    for (int ks = 0; ks < NK; ++ks) {
        if (ks + 1 < NK) {
            #pragma unroll
            for (int j = 0; j < NCB; ++j) {
                bn[j][0] = *(const short8v*)&wv[((j * NK + ks + 1) * 2 + 0) * 512 + lane * 8];
                bn[j][1] = *(const short8v*)&wv[((j * NK + ks + 1) * 2 + 1) * 512 + lane * 8];
            }
        }
        short8v ah[2], al[2];
        #pragma unroll
        for (int i = 0; i < 2; ++i) {
            int ro = (i * 16 + lr) * 264 + ks * 32 + kq;
            ah[i] = *(const short8v*)&Ah[ro];
            al[i] = *(const short8v*)&Al[ro];
        }
        #pragma unroll
        for (int i = 0; i < 2; ++i)
            #pragma unroll
            for (int j = 0; j < NCB; ++j) {
                acc[i][j] = __builtin_amdgcn_mfma_f32_16x16x32_bf16(ah[i], bc[j][0], acc[i][j], 0, 0, 0);
                acc[i][j] = __builtin_amdgcn_mfma_f32_16x16x32_bf16(ah[i], bc[j][1], acc[i][j], 0, 0, 0);
                acc[i][j] = __builtin_amdgcn_mfma_f32_16x16x32_bf16(al[i], bc[j][0], acc[i][j], 0, 0, 0);
            }
        if (ks + 1 < NK) {
            #pragma unroll
            for (int j = 0; j < NCB; ++j) { bc[j][0] = bn[j][0]; bc[j][1] = bn[j][1]; }
        }
    }
}

// ---------------------------------------------------------------------------
// Whole network, one block per 2 molecules (32 rows), 256 threads (4 waves).
// All intermediates in LDS. ~120 KB LDS -> 1 block/CU.
// ---------------------------------------------------------------------------
__global__ __launch_bounds__(256, 1)
void mega(const float* __restrict__ H, const unsigned short* __restrict__ wpk,
          const float* __restrict__ bl, const float* __restrict__ br,
          const float* __restrict__ att, const float* __restrict__ gbias,
          const float* __restrict__ gb1, const float* __restrict__ gb2,
          const float* __restrict__ gW3, const float* __restrict__ gb3,
          float* __restrict__ out) {
    __shared__ short sAh[32][264], sAl[32][264];   // A pairs (X, later h1)
    __shared__ float sL[32][260], sR[32][260];     // xl / xr (later h1f unused / h2)
    __shared__ float sXf[32][132];                 // X after layer 1 (for pool)
    __shared__ float sLog[2][32][20];              // logits -> alphas
    __shared__ float sg[32], ssc[32];

    int tid  = threadIdx.x;
    int lane = tid & 63;
    int w    = tid >> 6;
    int lr   = lane & 15;
    int rowBase = blockIdx.x * 32;
    int m2 = tid >> 7;
    int rr = tid & 127;

    // ---- stage H -> bf16 hi/lo pairs in LDS ----
    {
        int r = tid >> 3, q = tid & 7;
        const float* hp = H + (size_t)(rowBase + r) * 128 + q * 16;
        #pragma unroll
        for (int u = 0; u < 4; ++u) {
            f32x4 v = *(const f32x4*)&hp[u * 4];
            unsigned short h0 = f2bf(v[0]), h1 = f2bf(v[1]), h2 = f2bf(v[2]), h3 = f2bf(v[3]);
            *(short4*)&sAh[r][q * 16 + u * 4] = make_short4((short)h0, (short)h1, (short)h2, (short)h3);
            *(short4*)&sAl[r][q * 16 + u * 4] = make_short4(
                (short)f2bf(v[0] - bf2f(h0)), (short)f2bf(v[1] - bf2f(h1)),
                (short)f2bf(v[2] - bf2f(h2)), (short)f2bf(v[3] - bf2f(h3)));
        }
    }
    __syncthreads();

    // ================= 2 GAT layers =================
    for (int l = 0; l < 2; ++l) {
        // ---- xl|xr GEMM: wave w covers cols w*128 of [xl(256)|xr(256)] ----
        {
            f32x4 acc[2][8];
            #pragma unroll
            for (int i = 0; i < 2; ++i)
                #pragma unroll
                for (int j = 0; j < 8; ++j) acc[i][j] = (f32x4){0.f, 0.f, 0.f, 0.f};
            tile_gemm<4, 8>(&sAh[0][0], &sAl[0][0],
                            wpk + (size_t)l * 131072 + (size_t)w * 32768, acc, lane);
            float* dst; int cbase; const float* bp;
            if (w < 2) { dst = &sL[0][0]; cbase = w * 128; bp = bl + l * 256 + w * 128; }
            else       { dst = &sR[0][0]; cbase = (w - 2) * 128; bp = br + l * 256 + (w - 2) * 128; }
            #pragma unroll
            for (int i = 0; i < 2; ++i) {
                int row0 = i * 16 + (lane >> 4) * 4;
                #pragma unroll
                for (int j = 0; j < 8; ++j) {
                    int cl = j * 16 + lr;
                    float bv = bp[cl];
                    #pragma unroll
                    for (int t = 0; t < 4; ++t)
                        dst[(row0 + t) * 260 + cbase + cl] = acc[i][j][t] + bv;
                }
            }
        }
        __syncthreads();

        // ---- logits: thread = (m2, dh, cq); leaky(x,.2) = .6x + .4|x| ----
        {
            int dh = rr >> 2, cq = rr & 3;
            int dd = dh >> 1, hh = dh & 1;
            f32x4 a6[8], a4[8], xr4[8];
            const float* ap = att + l * 256 + hh * 128 + cq * 32;
            const float* xp = &sR[m2 * 16 + dd][hh * 128 + cq * 32];
            #pragma unroll
            for (int q = 0; q < 8; ++q) {
                f32x4 a = *(const f32x4*)&ap[q * 4];
                a6[q] = a * 0.6f;
                a4[q] = a * 0.4f;
                xr4[q] = *(const f32x4*)&xp[q * 4];
            }
            for (int s = 0; s < 16; ++s) {
                const float* xlp = &sL[m2 * 16 + s][hh * 128 + cq * 32];
                float ac = 0.f;
                #pragma unroll
                for (int q = 0; q < 8; ++q) {
                    f32x4 x = *(const f32x4*)&xlp[q * 4];
                    f32x4 e = x + xr4[q];
                    ac += a6[q][0] * e[0] + a4[q][0] * fabsf(e[0]);
                    ac += a6[q][1] * e[1] + a4[q][1] * fabsf(e[1]);
                    ac += a6[q][2] * e[2] + a4[q][2] * fabsf(e[2]);
                    ac += a6[q][3] * e[3] + a4[q][3] * fabsf(e[3]);
                }
                ac += __shfl_down(ac, 2);
                ac += __shfl_down(ac, 1);
                if ((tid & 3) == 0) sLog[m2][dh][s] = ac;
            }
        }
        __syncthreads();

        // ---- softmax over s per (mol, d, h): one wave ----
        if (tid < 64) {
            int ms = tid >> 5, dhs = tid & 31;
            float vb[16], mx = -1e30f;
            #pragma unroll
            for (int s = 0; s < 16; ++s) { vb[s] = sLog[ms][dhs][s]; mx = fmaxf(mx, vb[s]); }
            float den = 0.f;
            #pragma unroll
            for (int s = 0; s < 16; ++s) { vb[s] = expf(vb[s] - mx); den += vb[s]; }
            float inv = 1.f / den;
            #pragma unroll
            for (int s = 0; s < 16; ++s) sLog[ms][dhs][s] = vb[s] * inv;
        }
        __syncthreads();

        // ---- aggregation: thread = (m2, dq, c4), 4 d's each ----
        {
            int c4 = rr & 31, dq = rr >> 5;
            f32x4 fa[4];
            fa[0] = fa[1] = fa[2] = fa[3] = (f32x4){0.f, 0.f, 0.f, 0.f};
            #pragma unroll
            for (int hh = 0; hh < 2; ++hh) {
                #pragma unroll
                for (int sq = 0; sq < 4; ++sq) {
                    f32x4 xv[4];
                    #pragma unroll
                    for (int si = 0; si < 4; ++si)
                        xv[si] = *(const f32x4*)&sL[m2 * 16 + sq * 4 + si][hh * 128 + c4 * 4];
                    #pragma unroll
                    for (int u = 0; u < 4; ++u) {
                        f32x4 al = *(const f32x4*)&sLog[m2][(u * 4 + dq) * 2 + hh][sq * 4];
                        fa[u] += al[0] * xv[0] + al[1] * xv[1] + al[2] * xv[2] + al[3] * xv[3];
                    }
                }
            }
            f32x4 bvv = *(const f32x4*)&gbias[l * 128 + c4 * 4];
            #pragma unroll
            for (int u = 0; u < 4; ++u) {
                int row = m2 * 16 + u * 4 + dq;
                f32x4 o = fa[u] * 0.5f + bvv;
                unsigned short h0 = f2bf(o[0]), h1 = f2bf(o[1]), h2 = f2bf(o[2]), h3 = f2bf(o[3]);
                *(short4*)&sAh[row][c4 * 4] = make_short4((short)h0, (short)h1, (short)h2, (short)h3);
                *(short4*)&sAl[row][c4 * 4] = make_short4(
                    (short)f2bf(o[0] - bf2f(h0)), (short)f2bf(o[1] - bf2f(h1)),
                    (short)f2bf(o[2] - bf2f(h2)), (short)f2bf(o[3] - bf2f(h3)));
                if (l == 1) *(f32x4*)&sXf[row][c4 * 4] = o;
            }
        }
        __syncthreads();
    }

    // ================= gate MLP =================
    // MLP1: h1 = leaky(X@gW1+gb1, .01) -> pairs back into sAh/sAl (cols 0..255)
    {
        f32x4 acc[2][4];
        #pragma unroll
        for (int i = 0; i < 2; ++i)
            #pragma unroll
            for (int j = 0; j < 4; ++j) acc[i][j] = (f32x4){0.f, 0.f, 0.f, 0.f};
        tile_gemm<4, 4>(&sAh[0][0], &sAl[0][0],
                        wpk + 262144 + (size_t)w * 16384, acc, lane);
        __syncthreads();   // all A reads complete before overwriting sAh
        #pragma unroll
        for (int i = 0; i < 2; ++i) {
            int row0 = i * 16 + (lane >> 4) * 4;
            #pragma unroll
            for (int j = 0; j < 4; ++j) {
                int cl = w * 64 + j * 16 + lr;
                float bv = gb1[cl];
                #pragma unroll
                for (int t = 0; t < 4; ++t) {
                    float v = acc[i][j][t] + bv;
                    v = v >= 0.f ? v : 0.01f * v;
                    unsigned short h = f2bf(v);
                    sAh[row0 + t][cl] = (short)h;
                    sAl[row0 + t][cl] = (short)f2bf(v - bf2f(h));
                }
            }
        }
    }
    __syncthreads();

    // MLP2: h2 = leaky(h1@gW2+gb2, .01) -> sR fp32
    {
        f32x4 acc[2][4];
        #pragma unroll
        for (int i = 0; i < 2; ++i)
            #pragma unroll
            for (int j = 0; j < 4; ++j) acc[i][j] = (f32x4){0.f, 0.f, 0.f, 0.f};
        tile_gemm<8, 4>(&sAh[0][0], &sAl[0][0],
                        wpk + 327680 + (size_t)w * 32768, acc, lane);
        #pragma unroll
        for (int i = 0; i < 2; ++i) {
            int row0 = i * 16 + (lane >> 4) * 4;
            #pragma unroll
            for (int j = 0; j < 4; ++j) {
                int cl = w * 64 + j * 16 + lr;
                float bv = gb2[cl];
                #pragma unroll
                for (int t = 0; t < 4; ++t) {
                    float v = acc[i][j][t] + bv;
                    v = v >= 0.f ? v : 0.01f * v;
                    sR[row0 + t][cl] = v;
                }
            }
        }
    }
    __syncthreads();

    // ---- gate dot: g[row] = h2[row]·gW3 + gb3 ----
    {
        int grow = tid >> 3, l8 = tid & 7;
        float p = 0.f;
        #pragma unroll
        for (int t = 0; t < 8; ++t) {
            int c4g = l8 + t * 8;
            f32x4 h2v = *(const f32x4*)&sR[grow][c4g * 4];
            f32x4 w3v = *(const f32x4*)&gW3[c4g * 4];
            p += h2v[0] * w3v[0] + h2v[1] * w3v[1] + h2v[2] * w3v[2] + h2v[3] * w3v[3];
        }
        p += __shfl_down(p, 4);
        p += __shfl_down(p, 2);
        p += __shfl_down(p, 1);
        if (l8 == 0) sg[grow] = p + gb3[0];
    }
    __syncthreads();

    // ---- segment softmax (16-wide) + scores ----
    if (tid < 32) {
        float v = sg[tid];
        float mx = v;
        #pragma unroll
        for (int off = 8; off; off >>= 1) mx = fmaxf(mx, __shfl_xor(mx, off, 16));
        float e = expf(v - mx);
        float den = e;
        #pragma unroll
        for (int off = 8; off; off >>= 1) den += __shfl_xor(den, off, 16);
        float sc = e / den;
        ssc[tid] = sc;
        out[131072 + rowBase + tid] = sc;
    }
    __syncthreads();

    // ---- pool: h_pool[mol] = sum_s score[s] * X[s] ----
    {
        int cc = tid & 127;
        int mp = tid >> 7;
        float a = 0.f;
        #pragma unroll
        for (int s = 0; s < 16; ++s)
            a += ssc[mp * 16 + s] * sXf[mp * 16 + s][cc];
        out[(size_t)(blockIdx.x * 2 + mp) * 128 + cc] = a;
    }
}

// ---------------------------------------------------------------------------
extern "C" void kernel_launch(void* const* d_in, const int* in_sizes, int n_in,
                              void* d_out, int out_size, void* d_ws, size_t ws_size,
                              hipStream_t stream) {
    (void)in_sizes; (void)n_in; (void)out_size; (void)ws_size;
    const float* H        = (const float*)d_in[0];
    const float* Wl       = (const float*)d_in[4];
    const float* bl       = (const float*)d_in[5];
    const float* Wr       = (const float*)d_in[6];
    const float* br       = (const float*)d_in[7];
    const float* att      = (const float*)d_in[8];
    const float* gat_bias = (const float*)d_in[9];
    const float* gW1      = (const float*)d_in[10];
    const float* gb1      = (const float*)d_in[11];
    const float* gW2      = (const float*)d_in[12];
    const float* gb2      = (const float*)d_in[13];
    const float* gW3      = (const float*)d_in[14];
    const float* gb3      = (const float*)d_in[15];
    float* out = (float*)d_out;

    unsigned short* wpk = (unsigned short*)d_ws;   // 458752 shorts

    conv_pack<<<896, 256, 0, stream>>>(Wl, Wr, gW1, gW2, wpk);
    mega<<<512, 256, 0, stream>>>(H, wpk, bl, br, att, gat_bias,
                                  gb1, gb2, gW3, gb3, out);
}

// Round 7
// 65.885 us; speedup vs baseline: 3.2794x; 1.2516x over previous
//
#include <hip/hip_runtime.h>
#include <hip/hip_bf16.h>
#include <math.h>

#define N_NODES 16384
#define B_MOL   1024

typedef __attribute__((ext_vector_type(8))) short short8v;
typedef __attribute__((ext_vector_type(4))) float f32x4;

static __device__ __forceinline__ unsigned short f2bf(float f) {
    unsigned int u = __float_as_uint(f);
    unsigned int r = (u + 0x7FFFu + ((u >> 16) & 1u)) >> 16;   // RNE
    return (unsigned short)r;
}
static __device__ __forceinline__ float bf2f(unsigned short h) {
    return __uint_as_float(((unsigned int)h) << 16);
}

// ---------------------------------------------------------------------------
// Pack all weights into MFMA-fragment order, bf16 hi/lo.
// Fragment = (colblk of 16 cols) x (kstep of 32 k): 512 shorts, lane-major:
//   lane = (kk>>3)*16 + (col&15), pos = kk&7  ->  wave load = lane*8, coalesced.
// Matrix layout: frag index = (cb*nK + ks)*2 + hl, each 512 shorts.
// Segments (short offsets): L0 (512x128) @0, L1 @131072, M1 (256x128) @262144,
// M2 (256x256) @327680.
// ---------------------------------------------------------------------------
__global__ __launch_bounds__(256)
void conv_pack(const float* __restrict__ Wl, const float* __restrict__ Wr,
               const float* __restrict__ g1, const float* __restrict__ g2,
               unsigned short* __restrict__ wpk) {
    int idx = blockIdx.x * 256 + threadIdx.x;
    if (idx >= 229376) return;
    float v; size_t base; int nK, k, col;
    if (idx < 131072) {                      // layers 0/1: 512 cols x 128 k
        int l = idx >> 16;
        int e = idx & 65535;
        k = e >> 9; col = e & 511;
        v = (col < 256) ? Wl[l * 32768 + k * 256 + col]
                        : Wr[l * 32768 + k * 256 + (col - 256)];
        base = (size_t)l * 131072; nK = 4;
    } else if (idx < 163840) {               // MLP1: 256 x 128
        int e = idx - 131072; k = e >> 8; col = e & 255;
        v = g1[k * 256 + col]; base = 262144; nK = 4;
    } else {                                 // MLP2: 256 x 256
        int e = idx - 163840; k = e >> 8; col = e & 255;
        v = g2[k * 256 + col]; base = 327680; nK = 8;
    }
    int cb = col >> 4, ci = col & 15, ks = k >> 5, kk = k & 31;
    int lane = ((kk >> 3) << 4) | ci;
    size_t fo = ((size_t)(cb * nK + ks) * 2) * 512 + lane * 8 + (kk & 7);
    unsigned short h = f2bf(v);
    wpk[base + fo] = h;
    wpk[base + fo + 512] = f2bf(v - bf2f(h));
}

// ---------------------------------------------------------------------------
// Wave-tile GEMM: 32 rows x (NCB*16) cols, K = NK*32. A (bf16 hi/lo pairs)
// from LDS [32][264]; B from frag-packed global (register double-buffered).
// Split-bf16: acc += ah*bh + ah*bl + al*bh.
// ---------------------------------------------------------------------------
template<int NK, int NCB>
static __device__ __forceinline__ void tile_gemm(
        const short* __restrict__ Ah, const short* __restrict__ Al,
        const unsigned short* __restrict__ wv,
        f32x4 (&acc)[2][NCB], int lane) {
    int lr = lane & 15;
    int kq = (lane >> 4) * 8;
    short8v bc[NCB][2], bn[NCB][2];
    #pragma unroll
    for (int j = 0; j < NCB; ++j) {
        bc[j][0] = *(const short8v*)&wv[((j * NK + 0) * 2 + 0) * 512 + lane * 8];
        bc[j][1] = *(const short8v*)&wv[((j * NK + 0) * 2 + 1) * 512 + lane * 8];
    }
    #pragma unroll
    for (int ks = 0; ks < NK; ++ks) {
        if (ks + 1 < NK) {
            #pragma unroll
            for (int j = 0; j < NCB; ++j) {
                bn[j][0] = *(const short8v*)&wv[((j * NK + ks + 1) * 2 + 0) * 512 + lane * 8];
                bn[j][1] = *(const short8v*)&wv[((j * NK + ks + 1) * 2 + 1) * 512 + lane * 8];
            }
        }
        short8v ah[2], al[2];
        #pragma unroll
        for (int i = 0; i < 2; ++i) {
            int ro = (i * 16 + lr) * 264 + ks * 32 + kq;
            ah[i] = *(const short8v*)&Ah[ro];
            al[i] = *(const short8v*)&Al[ro];
        }
        #pragma unroll
        for (int i = 0; i < 2; ++i)
            #pragma unroll
            for (int j = 0; j < NCB; ++j) {
                acc[i][j] = __builtin_amdgcn_mfma_f32_16x16x32_bf16(ah[i], bc[j][0], acc[i][j], 0, 0, 0);
                acc[i][j] = __builtin_amdgcn_mfma_f32_16x16x32_bf16(ah[i], bc[j][1], acc[i][j], 0, 0, 0);
                acc[i][j] = __builtin_amdgcn_mfma_f32_16x16x32_bf16(al[i], bc[j][0], acc[i][j], 0, 0, 0);
            }
        if (ks + 1 < NK) {
            #pragma unroll
            for (int j = 0; j < NCB; ++j) { bc[j][0] = bn[j][0]; bc[j][1] = bn[j][1]; }
        }
    }
}

static __device__ __forceinline__ void pack_pair(f32x4 o, short4* ph, short4* pl) {
    unsigned short h0 = f2bf(o[0]), h1 = f2bf(o[1]), h2 = f2bf(o[2]), h3 = f2bf(o[3]);
    *ph = make_short4((short)h0, (short)h1, (short)h2, (short)h3);
    *pl = make_short4((short)f2bf(o[0] - bf2f(h0)), (short)f2bf(o[1] - bf2f(h1)),
                      (short)f2bf(o[2] - bf2f(h2)), (short)f2bf(o[3] - bf2f(h3)));
}

// ---------------------------------------------------------------------------
// Whole network, one block per 2 molecules (32 rows), 512 threads (8 waves).
// All intermediates in LDS (~120 KB -> 1 block/CU, 2 waves/SIMD).
// ---------------------------------------------------------------------------
__global__ __launch_bounds__(512, 1)
void mega(const float* __restrict__ H, const unsigned short* __restrict__ wpk,
          const float* __restrict__ bl, const float* __restrict__ br,
          const float* __restrict__ att, const float* __restrict__ gbias,
          const float* __restrict__ gb1, const float* __restrict__ gb2,
          const float* __restrict__ gW3, const float* __restrict__ gb3,
          float* __restrict__ out) {
    __shared__ short sAh[32][264], sAl[32][264];   // A pairs (X, later h1)
    __shared__ float sL[32][260], sR[32][260];     // xl / xr (later -- / h2)
    __shared__ float sXf[32][132];                 // X after layer 1 (for pool)
    __shared__ float sLog[2][32][20];              // logits -> alphas
    __shared__ float sg[32], ssc[32];

    int tid  = threadIdx.x;
    int lane = tid & 63;
    int w    = tid >> 6;                 // wave 0..7
    int lr   = lane & 15;
    int rowBase = blockIdx.x * 32;

    // ---- stage H -> bf16 hi/lo pairs in LDS ----
    {
        int r = tid >> 4, q = tid & 15;       // 8 floats each
        const float* hp = H + (size_t)(rowBase + r) * 128 + q * 8;
        #pragma unroll
        for (int u = 0; u < 2; ++u) {
            f32x4 v = *(const f32x4*)&hp[u * 4];
            pack_pair(v, (short4*)&sAh[r][q * 8 + u * 4], (short4*)&sAl[r][q * 8 + u * 4]);
        }
    }
    __syncthreads();

    // ================= 2 GAT layers =================
    for (int l = 0; l < 2; ++l) {
        // ---- xl|xr GEMM: wave w covers 64 cols of [xl(256)|xr(256)] ----
        {
            f32x4 acc[2][4];
            #pragma unroll
            for (int i = 0; i < 2; ++i)
                #pragma unroll
                for (int j = 0; j < 4; ++j) acc[i][j] = (f32x4){0.f, 0.f, 0.f, 0.f};
            tile_gemm<4, 4>(&sAh[0][0], &sAl[0][0],
                            wpk + (size_t)l * 131072 + (size_t)w * 16384, acc, lane);
            float* dst; int cbase; const float* bp;
            if (w < 4) { dst = &sL[0][0]; cbase = w * 64; bp = bl + l * 256 + w * 64; }
            else       { dst = &sR[0][0]; cbase = (w - 4) * 64; bp = br + l * 256 + (w - 4) * 64; }
            #pragma unroll
            for (int i = 0; i < 2; ++i) {
                int row0 = i * 16 + (lane >> 4) * 4;
                #pragma unroll
                for (int j = 0; j < 4; ++j) {
                    int cl = j * 16 + lr;
                    float bv = bp[cl];
                    #pragma unroll
                    for (int t = 0; t < 4; ++t)
                        dst[(row0 + t) * 260 + cbase + cl] = acc[i][j][t] + bv;
                }
            }
        }
        __syncthreads();

        // ---- logits: thread = (m2, h, dblk, sblk, cq); 4x4 (d,s) reg tile,
        //      16 channels per thread (chunks staggered by cq to spread banks);
        //      leaky(x,.2) = .6x + .4|x| ----
        {
            int m2l = tid >> 8;
            int r8  = tid & 255;
            int hh  = r8 >> 7;
            int db  = (r8 >> 5) & 3;
            int sb  = (r8 >> 3) & 3;
            int cq  = r8 & 7;
            float ac[4][4];
            #pragma unroll
            for (int di = 0; di < 4; ++di)
                #pragma unroll
                for (int si = 0; si < 4; ++si) ac[di][si] = 0.f;
            #pragma unroll
            for (int t = 0; t < 4; ++t) {
                int c4 = cq + 8 * t;                         // f32x4 index in head slice
                f32x4 av = *(const f32x4*)&att[l * 256 + hh * 128 + c4 * 4];
                f32x4 a6 = av * 0.6f, a4 = av * 0.4f;
                f32x4 xrv[4], xlv[4];
                #pragma unroll
                for (int di = 0; di < 4; ++di)
                    xrv[di] = *(const f32x4*)&sR[m2l * 16 + db * 4 + di][hh * 128 + c4 * 4];
                #pragma unroll
                for (int si = 0; si < 4; ++si)
                    xlv[si] = *(const f32x4*)&sL[m2l * 16 + sb * 4 + si][hh * 128 + c4 * 4];
                #pragma unroll
                for (int di = 0; di < 4; ++di)
                    #pragma unroll
                    for (int si = 0; si < 4; ++si) {
                        f32x4 e = xlv[si] + xrv[di];
                        ac[di][si] += a6[0] * e[0] + a4[0] * fabsf(e[0])
                                    + a6[1] * e[1] + a4[1] * fabsf(e[1])
                                    + a6[2] * e[2] + a4[2] * fabsf(e[2])
                                    + a6[3] * e[3] + a4[3] * fabsf(e[3]);
                    }
            }
            #pragma unroll
            for (int di = 0; di < 4; ++di)
                #pragma unroll
                for (int si = 0; si < 4; ++si) {
                    float v = ac[di][si];
                    v += __shfl_down(v, 4);
                    v += __shfl_down(v, 2);
                    v += __shfl_down(v, 1);
                    if (cq == 0)
                        sLog[m2l][(db * 4 + di) * 2 + hh][sb * 4 + si] = v;
                }
        }
        __syncthreads();

        // ---- softmax over s per (mol, d, h): one wave ----
        if (tid < 64) {
            int ms = tid >> 5, dhs = tid & 31;
            float vb[16], mx = -1e30f;
            #pragma unroll
            for (int s = 0; s < 16; ++s) { vb[s] = sLog[ms][dhs][s]; mx = fmaxf(mx, vb[s]); }
            float den = 0.f;
            #pragma unroll
            for (int s = 0; s < 16; ++s) { vb[s] = expf(vb[s] - mx); den += vb[s]; }
            float inv = 1.f / den;
            #pragma unroll
            for (int s = 0; s < 16; ++s) sLog[ms][dhs][s] = vb[s] * inv;
        }
        __syncthreads();

        // ---- aggregation: thread = (m2, d, cw); s rotated by cw (bank spread) ----
        {
            int m2a = tid >> 8;
            int d  = (tid >> 4) & 15;
            int cw = tid & 15;
            f32x4 f0 = (f32x4){0.f, 0.f, 0.f, 0.f};
            f32x4 f1 = (f32x4){0.f, 0.f, 0.f, 0.f};
            #pragma unroll
            for (int hh = 0; hh < 2; ++hh) {
                const float* alr = &sLog[m2a][d * 2 + hh][0];
                #pragma unroll
                for (int s = 0; s < 16; ++s) {
                    int se = (s + cw) & 15;
                    float al = alr[se];
                    const float* xp = &sL[m2a * 16 + se][hh * 128 + cw * 8];
                    f0 += al * *(const f32x4*)xp;
                    f1 += al * *(const f32x4*)(xp + 4);
                }
            }
            f32x4 o0 = f0 * 0.5f + *(const f32x4*)&gbias[l * 128 + cw * 8];
            f32x4 o1 = f1 * 0.5f + *(const f32x4*)&gbias[l * 128 + cw * 8 + 4];
            int row = m2a * 16 + d;
            pack_pair(o0, (short4*)&sAh[row][cw * 8],     (short4*)&sAl[row][cw * 8]);
            pack_pair(o1, (short4*)&sAh[row][cw * 8 + 4], (short4*)&sAl[row][cw * 8 + 4]);
            if (l == 1) {
                *(f32x4*)&sXf[row][cw * 8]     = o0;
                *(f32x4*)&sXf[row][cw * 8 + 4] = o1;
            }
        }
        __syncthreads();
    }

    // ================= gate MLP =================
    // MLP1: h1 = leaky(X@gW1+gb1, .01) -> pairs back into sAh/sAl
    {
        f32x4 acc[2][2];
        #pragma unroll
        for (int i = 0; i < 2; ++i)
            #pragma unroll
            for (int j = 0; j < 2; ++j) acc[i][j] = (f32x4){0.f, 0.f, 0.f, 0.f};
        tile_gemm<4, 2>(&sAh[0][0], &sAl[0][0],
                        wpk + 262144 + (size_t)w * 8192, acc, lane);
        __syncthreads();   // all A reads complete before overwriting sAh
        #pragma unroll
        for (int i = 0; i < 2; ++i) {
            int row0 = i * 16 + (lane >> 4) * 4;
            #pragma unroll
            for (int j = 0; j < 2; ++j) {
                int cl = w * 32 + j * 16 + lr;
                float bv = gb1[cl];
                #pragma unroll
                for (int t = 0; t < 4; ++t) {
                    float v = acc[i][j][t] + bv;
                    v = v >= 0.f ? v : 0.01f * v;
                    unsigned short h = f2bf(v);
                    sAh[row0 + t][cl] = (short)h;
                    sAl[row0 + t][cl] = (short)f2bf(v - bf2f(h));
                }
            }
        }
    }
    __syncthreads();

    // MLP2: h2 = leaky(h1@gW2+gb2, .01) -> sR fp32
    {
        f32x4 acc[2][2];
        #pragma unroll
        for (int i = 0; i < 2; ++i)
            #pragma unroll
            for (int j = 0; j < 2; ++j) acc[i][j] = (f32x4){0.f, 0.f, 0.f, 0.f};
        tile_gemm<8, 2>(&sAh[0][0], &sAl[0][0],
                        wpk + 327680 + (size_t)w * 16384, acc, lane);
        #pragma unroll
        for (int i = 0; i < 2; ++i) {
            int row0 = i * 16 + (lane >> 4) * 4;
            #pragma unroll
            for (int j = 0; j < 2; ++j) {
                int cl = w * 32 + j * 16 + lr;
                float bv = gb2[cl];
                #pragma unroll
                for (int t = 0; t < 4; ++t) {
                    float v = acc[i][j][t] + bv;
                    v = v >= 0.f ? v : 0.01f * v;
                    sR[row0 + t][cl] = v;
                }
            }
        }
    }
    __syncthreads();

    // ---- gate dot: g[row] = h2[row]·gW3 + gb3 ----
    {
        int grow = tid >> 4, l16 = tid & 15;
        float p = 0.f;
        #pragma unroll
        for (int u = 0; u < 4; ++u) {
            f32x4 h2v = *(const f32x4*)&sR[grow][l16 * 16 + u * 4];
            f32x4 w3v = *(const f32x4*)&gW3[l16 * 16 + u * 4];
            p += h2v[0] * w3v[0] + h2v[1] * w3v[1] + h2v[2] * w3v[2] + h2v[3] * w3v[3];
        }
        p += __shfl_down(p, 8);
        p += __shfl_down(p, 4);
        p += __shfl_down(p, 2);
        p += __shfl_down(p, 1);
        if (l16 == 0) sg[grow] = p + gb3[0];
    }
    __syncthreads();

    // ---- segment softmax (16-wide) + scores ----
    if (tid < 32) {
        float v = sg[tid];
        float mx = v;
        #pragma unroll
        for (int off = 8; off; off >>= 1) mx = fmaxf(mx, __shfl_xor(mx, off, 16));
        float e = expf(v - mx);
        float den = e;
        #pragma unroll
        for (int off = 8; off; off >>= 1) den += __shfl_xor(den, off, 16);
        float sc = e / den;
        ssc[tid] = sc;
        out[131072 + rowBase + tid] = sc;
    }
    __syncthreads();

    // ---- pool: h_pool[mol] = sum_s score[s] * X[s] ----
    if (tid < 256) {
        int cc = tid & 127;
        int mp = tid >> 7;
        float a = 0.f;
        #pragma unroll
        for (int s = 0; s < 16; ++s)
            a += ssc[mp * 16 + s] * sXf[mp * 16 + s][cc];
        out[(size_t)(blockIdx.x * 2 + mp) * 128 + cc] = a;
    }
}

// ---------------------------------------------------------------------------
extern "C" void kernel_launch(void* const* d_in, const int* in_sizes, int n_in,
                              void* d_out, int out_size, void* d_ws, size_t ws_size,
                              hipStream_t stream) {
    (void)in_sizes; (void)n_in; (void)out_size; (void)ws_size;
    const float* H        = (const float*)d_in[0];
    const float* Wl       = (const float*)d_in[4];
    const float* bl       = (const float*)d_in[5];
    const float* Wr       = (const float*)d_in[6];
    const float* br       = (const float*)d_in[7];
    const float* att      = (const float*)d_in[8];
    const float* gat_bias = (const float*)d_in[9];
    const float* gW1      = (const float*)d_in[10];
    const float* gb1      = (const float*)d_in[11];
    const float* gW2      = (const float*)d_in[12];
    const float* gb2      = (const float*)d_in[13];
    const float* gW3      = (const float*)d_in[14];
    const float* gb3      = (const float*)d_in[15];
    float* out = (float*)d_out;

    unsigned short* wpk = (unsigned short*)d_ws;   // 458752 shorts

    conv_pack<<<896, 256, 0, stream>>>(Wl, Wr, gW1, gW2, wpk);
    mega<<<512, 512, 0, stream>>>(H, wpk, bl, br, att, gat_bias,
                                  gb1, gb2, gW3, gb3, out);
}